// Round 2
// baseline (150.077 us; speedup 1.0000x reference)
//
#include <hip/hip_runtime.h>

#define TT    2048
#define SS    512
#define NB    16
#define EPEN  0.60653065971263342f   // exp(-0.5)
#define NCHUNK 64
#define CLEN   32

typedef __attribute__((ext_vector_type(4))) float  floatx4;
typedef __attribute__((ext_vector_type(8))) short  bf16x8;

__device__ __forceinline__ ushort f2bf(float x) {   // RNE fp32 -> bf16
  unsigned u = __float_as_uint(x);
  u += 0x7fffu + ((u >> 16) & 1u);
  return (ushort)(u >> 16);
}

// ---------------- kernel 0: W -> transposed bf16  Wt[col][k] ---------------
__global__ __launch_bounds__(256) void prep_kernel(
    const float* __restrict__ Wa, const float* __restrict__ Ws,
    const float* __restrict__ Wst, ushort* __restrict__ Wt)
{
  int idx = blockIdx.x * 256 + threadIdx.x;       // 336*512 = 172032
  if (idx >= 336 * 512) return;
  int col = idx >> 9, k = idx & 511;
  float v;
  if (col < 288)      v = Wa [(size_t)k * 288 + col];
  else if (col < 320) v = Ws [(size_t)k * 32  + (col - 288)];
  else                v = Wst[(size_t)k * 16  + (col - 320)];
  Wt[idx] = f2bf(v);
}

// ---------------- kernel A: MFMA GEMM + softmax -> coef --------------------
// block: 32 rows x 336 cols, 4 waves. wave m-tile = (wave>>1), n-tiles split
// even wave: col-tiles 0..10, odd wave: 11..20.
// Double-buffered LDS staging: ONE barrier per k-tile; global loads for tile
// kt+1 are issued before the barrier so their latency hides under the
// barrier-wait + ds_read + MFMA phase of tile kt.
__global__ __launch_bounds__(256) void proj_kernel(
    const float* __restrict__ s_i,
    const ushort* __restrict__ Wt,
    const int*   __restrict__ actions,
    float4*      __restrict__ coef)
{
  __shared__ ushort At[2][32 * 40];     // row stride 40 halves (80 B)
  __shared__ ushort Bt[2][336 * 40];    // col stride 40 halves
  __shared__ float  lg[32][344];

  const int tid  = threadIdx.x;
  const int wave = tid >> 6, lane = tid & 63;
  const int q = lane >> 4, rc = lane & 15;
  const int row0 = blockIdx.x * 32;

  const int mbase  = (wave >> 1) * 16;
  const int ntile0 = (wave & 1) * 11;
  const int ntiles = (wave & 1) ? 10 : 11;

  floatx4 acc[11];
  #pragma unroll
  for (int n = 0; n < 11; ++n) acc[n] = (floatx4)(0.f);

  const int ar  = tid >> 3, akq = tid & 7;        // A staging: row, 4-float chunk
  int agrow = row0 + ar; if (agrow > TT) agrow = TT;
  const float* aptr = s_i + (size_t)agrow * SS + akq * 4;

  // ---- prologue: load + write tile 0
  {
    float4 av = *(const float4*)(aptr);
    ushort4 h; h.x = f2bf(av.x); h.y = f2bf(av.y); h.z = f2bf(av.z); h.w = f2bf(av.w);
    *(ushort4*)(&At[0][ar * 40 + akq * 4]) = h;
    #pragma unroll
    for (int i = 0; i < 6; ++i) {
      int idx = i * 256 + tid;
      if (idx < 1344) {
        int col = idx >> 2, ch = idx & 3;
        uint4 v = *(const uint4*)(Wt + (size_t)col * 512 + ch * 8);
        *(uint4*)(&Bt[0][col * 40 + ch * 8]) = v;
      }
    }
  }

  for (int kt = 0; kt < 16; ++kt) {
    const int cur = kt & 1;
    // ---- issue next tile's global loads (no use yet -> stay in flight)
    float4 av_n;
    uint4  bv_n[6];
    if (kt < 15) {
      av_n = *(const float4*)(aptr + (kt + 1) * 32);
      #pragma unroll
      for (int i = 0; i < 6; ++i) {
        int idx = i * 256 + tid;
        if (idx < 1344) {
          int col = idx >> 2, ch = idx & 3;
          bv_n[i] = *(const uint4*)(Wt + (size_t)col * 512 + (kt + 1) * 32 + ch * 8);
        }
      }
    }
    __syncthreads();            // buf[cur] writes visible to all waves

    bf16x8 afrag = *(bf16x8*)(&At[cur][(mbase + rc) * 40 + q * 8]);
    #pragma unroll
    for (int n = 0; n < 11; ++n) {
      if (n < ntiles) {
        int colt = ntile0 + n;
        bf16x8 bfrag = *(bf16x8*)(&Bt[cur][(colt * 16 + rc) * 40 + q * 8]);
        acc[n] = __builtin_amdgcn_mfma_f32_16x16x32_bf16(afrag, bfrag, acc[n], 0, 0, 0);
      }
    }

    // ---- write next tile into the other buffer (vmcnt wait lands here)
    if (kt < 15) {
      ushort4 h; h.x = f2bf(av_n.x); h.y = f2bf(av_n.y); h.z = f2bf(av_n.z); h.w = f2bf(av_n.w);
      *(ushort4*)(&At[cur ^ 1][ar * 40 + akq * 4]) = h;
      #pragma unroll
      for (int i = 0; i < 6; ++i) {
        int idx = i * 256 + tid;
        if (idx < 1344) {
          int col = idx >> 2, ch = idx & 3;
          *(uint4*)(&Bt[cur ^ 1][col * 40 + ch * 8]) = bv_n[i];
        }
      }
    }
  }

  // ---- write logits to LDS (C/D layout: row = q*4+reg, col = rc)
  #pragma unroll
  for (int n = 0; n < 11; ++n) {
    if (n < ntiles) {
      int colt = ntile0 + n;
      #pragma unroll
      for (int reg = 0; reg < 4; ++reg)
        lg[mbase + q * 4 + reg][colt * 16 + rc] = acc[n][reg];
    }
  }
  __syncthreads();

  // ---- softmax epilogue: 32 rows x 16 b, two passes of 256 threads
  #pragma unroll
  for (int h = 0; h < 2; ++h) {
    const int r = h * 16 + (tid >> 4), b = tid & 15;
    const int row = row0 + r;
    if (row < TT) {
      float m = -3.4e38f;
      #pragma unroll
      for (int a = 0; a < 18; ++a) m = fmaxf(m, lg[r][b * 18 + a]);
      float sum = 0.f;
      #pragma unroll
      for (int a = 0; a < 18; ++a) sum += __expf(lg[r][b * 18 + a] - m);
      int act = actions[row];
      float aprob = __expf(lg[r][b * 18 + act] - m) / sum;

      float x0 = lg[r][288 + 2 * b], x1 = lg[r][288 + 2 * b + 1];
      float mm = fmaxf(x0, x1);
      float e0 = __expf(x0 - mm), e1 = __expf(x1 - mm);
      float inv = 1.f / (e0 + e1);

      float ms = -3.4e38f;
      #pragma unroll
      for (int j = 0; j < 16; ++j) ms = fmaxf(ms, lg[r][320 + j]);
      float ssum = 0.f;
      #pragma unroll
      for (int j = 0; j < 16; ++j) ssum += __expf(lg[r][320 + j] - ms);
      float stp = __expf(lg[r][320 + b] - ms) / ssum;

      coef[(size_t)row * NB + b] = make_float4(e0 * inv, e1 * inv, stp, aprob);
    } else if (row == TT) {
      // virtual step 2048: A = I, "action" prob = stop0 prob of row T
      float x0 = lg[r][288 + 2 * b], x1 = lg[r][288 + 2 * b + 1];
      float mm = fmaxf(x0, x1);
      float e0 = __expf(x0 - mm), e1 = __expf(x1 - mm);
      coef[(size_t)TT * NB + b] = make_float4(1.f, 0.f, 0.f, e0 / (e0 + e1));
    }
  }
}

// ---------------- kernel B: pass1 — chunk transfer matrices + w-vectors ----
__global__ __launch_bounds__(64) void pass1_kernel(
    const float4* __restrict__ coef,
    float* __restrict__ Wws, float* __restrict__ Mws)
{
  const int chunk = blockIdx.x * 4 + (threadIdx.x >> 4);
  const int c = threadIdx.x & 15;
  const int i0 = chunk * CLEN + 1;

  float G[16];
  #pragma unroll
  for (int r = 0; r < 16; ++r) G[r] = (r == c) ? 1.f : 0.f;

  float4 cfA[16], cfB[16];
  #pragma unroll
  for (int r = 0; r < 16; ++r) cfA[r] = coef[(size_t)i0 * 16 + r];
  #pragma unroll
  for (int r = 0; r < 16; ++r) cfB[r] = coef[(size_t)(i0 + 1) * 16 + r];

#define P1BODY(CUR, NXT, J)                                                  \
  {                                                                          \
    if ((J) + 2 < CLEN) {                                                    \
      _Pragma("unroll")                                                      \
      for (int r = 0; r < 16; ++r)                                           \
        NXT[r] = coef[(size_t)(i0 + (J) + 2) * 16 + r];                      \
    }                                                                        \
    float ta = 0.f, tb = 0.f, tc = 0.f, td = 0.f;                            \
    _Pragma("unroll")                                                        \
    for (int r = 0; r < 4; ++r) {                                            \
      ta = fmaf(CUR[r].y,      G[r],      ta);                               \
      tb = fmaf(CUR[r + 4].y,  G[r + 4],  tb);                               \
      tc = fmaf(CUR[r + 8].y,  G[r + 8],  tc);                               \
      td = fmaf(CUR[r + 12].y, G[r + 12], td);                               \
    }                                                                        \
    float et = EPEN * ((ta + tb) + (tc + td));                               \
    _Pragma("unroll")                                                        \
    for (int r = 0; r < 16; ++r)                                             \
      G[r] = fmaf(CUR[r].x, G[r], CUR[r].z * et);                            \
    float wa = 0.f, wb = 0.f, wc = 0.f, wd = 0.f;                            \
    _Pragma("unroll")                                                        \
    for (int r = 0; r < 4; ++r) {                                            \
      wa = fmaf(CUR[r].w,      G[r],      wa);                               \
      wb = fmaf(CUR[r + 4].w,  G[r + 4],  wb);                               \
      wc = fmaf(CUR[r + 8].w,  G[r + 8],  wc);                               \
      wd = fmaf(CUR[r + 12].w, G[r + 12], wd);                               \
    }                                                                        \
    Wws[(size_t)(chunk * CLEN + (J)) * 16 + c] = (wa + wb) + (wc + wd);      \
  }

  for (int j = 0; j < CLEN; j += 2) {
    P1BODY(cfA, cfB, j);
    P1BODY(cfB, cfA, j + 1);
  }
#undef P1BODY

  #pragma unroll
  for (int r = 0; r < 16; ++r)
    Mws[chunk * 256 + r * 16 + c] = G[r];
}

// ---------------- kernel C: pass2 — sequential chunk walk + term sums -----
// 256 threads (4 waves): thread (rr, c) owns steps rr and rr+16 of each
// chunk. Same math/order as the 512-thread version; barriers are 2x cheaper
// and the serial p-chain contends with fewer waves.
template <int N>
__device__ __forceinline__ float ror_add(float v) {
  int r = __builtin_amdgcn_mov_dpp(__float_as_int(v), 0x120 + N, 0xF, 0xF, true);
  return v + __int_as_float(r);
}
__device__ __forceinline__ float reduce16(float v) {
  v = ror_add<8>(v); v = ror_add<4>(v); v = ror_add<2>(v); v = ror_add<1>(v);
  return v;
}

__global__ __launch_bounds__(256) void pass2_kernel(
    const float4* __restrict__ coef,
    const float* __restrict__ Wws, const float* __restrict__ Mws,
    float* __restrict__ out)
{
  __shared__ float lds_p[2][16];
  __shared__ float lds_acc[16];
  const int tid = threadIdx.x;
  const int rr = tid >> 4, c = tid & 15;       // rr = 0..15

  float4 c0 = coef[c];
  float p = c0.z;
  float U0 = reduce16(c0.w * p);
  float acc = (tid == 0) ? __logf(U0) : 0.f;
  int Ecum = 0;
  long long Ktot = 0;

  float wbufA[4], wbufB[4], mbuf[4];
  #pragma unroll
  for (int q = 0; q < 4; ++q) {
    wbufA[q] = Wws[(size_t)(q * CLEN + rr) * 16 + c];
    wbufB[q] = Wws[(size_t)(q * CLEN + rr + 16) * 16 + c];
    mbuf[q]  = Mws[q * 256 + rr * 16 + c];
  }

  for (int kb = 0; kb < NCHUNK; kb += 4) {
    #pragma unroll
    for (int q = 0; q < 4; ++q) {
      const int k = kb + q;
      float wa = wbufA[q], wb = wbufB[q], mc = mbuf[q];
      if (k + 4 < NCHUNK) {
        wbufA[q] = Wws[(size_t)((k + 4) * CLEN + rr) * 16 + c];
        wbufB[q] = Wws[(size_t)((k + 4) * CLEN + rr + 16) * 16 + c];
        mbuf[q]  = Mws[(k + 4) * 256 + rr * 16 + c];
      }
      float Ua = reduce16(wa * p);
      float Ub = reduce16(wb * p);
      if (c == 0) acc += __logf(Ua) + __logf(Ub);
      Ktot += 32LL * (long long)Ecum;
      float y = reduce16(mc * p);
      if (c == 0) lds_p[k & 1][rr] = y;
      __syncthreads();
      float pn = lds_p[k & 1][c];
      float p0 = lds_p[k & 1][0];
      int eb = (__float_as_int(p0) >> 23) & 255;
      Ecum += eb - 127;
      p = pn * __int_as_float((254 - eb) << 23);
    }
  }

  if (c == 0) lds_acc[rr] = acc;
  __syncthreads();
  if (tid == 0) {
    double s = 0.0;
    #pragma unroll
    for (int i = 0; i < 16; ++i) s += (double)lds_acc[i];
    out[0] = (float)(s + 0.6931471805599453 * (double)Ktot);
  }
}

extern "C" void kernel_launch(void* const* d_in, const int* in_sizes, int n_in,
                              void* d_out, int out_size, void* d_ws, size_t ws_size,
                              hipStream_t stream) {
  const float* s_i = (const float*)d_in[0];
  const float* Wa  = (const float*)d_in[1];
  const float* Ws  = (const float*)d_in[2];
  const float* Wst = (const float*)d_in[3];
  const int*   act = (const int*)d_in[4];

  char* ws = (char*)d_ws;
  float4* coef = (float4*)ws;                        //   524,544 B
  float*  Wws  = (float*)(ws + 524544);              // + 131,072 B
  float*  Mws  = (float*)(ws + 524544 + 131072);     // +  65,536 B
  ushort* Wt   = (ushort*)(ws + 524544 + 131072 + 65536);  // + 344,064 B (total ~1.04 MB)

  prep_kernel <<<672, 256, 0, stream>>>(Wa, Ws, Wst, Wt);
  proj_kernel <<<65,  256, 0, stream>>>(s_i, Wt, act, coef);
  pass1_kernel<<<16,  64,  0, stream>>>(coef, Wws, Mws);
  pass2_kernel<<<1,   256, 0, stream>>>(coef, Wws, Mws, (float*)d_out);
}

// Round 3
// 130.948 us; speedup vs baseline: 1.1461x; 1.1461x over previous
//
#include <hip/hip_runtime.h>

#define TT    2048
#define SS    512
#define NB    16
#define EPEN  0.60653065971263342f   // exp(-0.5)
#define NCHUNK 64
#define CLEN   32

typedef __attribute__((ext_vector_type(4))) float  floatx4;
typedef __attribute__((ext_vector_type(8))) short  bf16x8;

__device__ __forceinline__ ushort f2bf(float x) {   // RNE fp32 -> bf16
  unsigned u = __float_as_uint(x);
  u += 0x7fffu + ((u >> 16) & 1u);
  return (ushort)(u >> 16);
}

// ---------------- kernel 0: W -> transposed bf16  Wt[col][k] ---------------
__global__ __launch_bounds__(256) void prep_kernel(
    const float* __restrict__ Wa, const float* __restrict__ Ws,
    const float* __restrict__ Wst, ushort* __restrict__ Wt)
{
  int idx = blockIdx.x * 256 + threadIdx.x;       // 336*512 = 172032
  if (idx >= 336 * 512) return;
  int col = idx >> 9, k = idx & 511;
  float v;
  if (col < 288)      v = Wa [(size_t)k * 288 + col];
  else if (col < 320) v = Ws [(size_t)k * 32  + (col - 288)];
  else                v = Wst[(size_t)k * 16  + (col - 320)];
  Wt[idx] = f2bf(v);
}

// ---------------- kernel A: MFMA GEMM + softmax -> coef --------------------
// 129 blocks x 16 rows, 4 waves/block. NO LDS staging, NO barrier in the
// k-loop: B fragments load directly from L2-resident Wt (344 KB) in MFMA
// fragment layout; A fragments load fp32 from s_i and convert in-register.
// Wave w owns n-tiles {w, w+4, w+8, ...} (wave 0: 6 tiles, others 5).
// 1-deep explicit software pipeline (cur/nxt), fully unrolled.
__global__ __launch_bounds__(256) void proj_kernel(
    const float* __restrict__ s_i,
    const ushort* __restrict__ Wt,
    const int*   __restrict__ actions,
    float4*      __restrict__ coef)
{
  __shared__ float lg[16][346];    // stride 346: 2-way bank aliasing (free)

  const int tid  = threadIdx.x;
  const int wave = tid >> 6, lane = tid & 63;
  const int q = lane >> 4, rc = lane & 15;
  const int row0 = blockIdx.x * 16;

  const int ntiles = (wave == 0) ? 6 : 5;

  int arow = row0 + rc; if (arow > TT) arow = TT;
  const float*  aRow  = s_i + (size_t)arow * SS + q * 8;
  const ushort* bBase = Wt + (size_t)rc * 512 + q * 8;

  floatx4 acc[6];
  #pragma unroll
  for (int j = 0; j < 6; ++j) acc[j] = (floatx4)(0.f);

  float4 a0C, a1C, a0N, a1N;
  bf16x8 bC[6], bN[6];

  // ---- prologue: load k-tile 0 fragments
  a0C = *(const float4*)(aRow + 0);
  a1C = *(const float4*)(aRow + 4);
  #pragma unroll
  for (int j = 0; j < 6; ++j) {
    if (j < ntiles) {
      const int colt = wave + 4 * j;
      bC[j] = *(const bf16x8*)(bBase + (size_t)colt * (16 * 512));
    }
  }

  #pragma unroll
  for (int kt = 0; kt < 16; ++kt) {
    // ---- issue next k-tile's loads (stay in flight under the MFMAs)
    if (kt < 15) {
      a0N = *(const float4*)(aRow + (kt + 1) * 32);
      a1N = *(const float4*)(aRow + (kt + 1) * 32 + 4);
      #pragma unroll
      for (int j = 0; j < 6; ++j) {
        if (j < ntiles) {
          const int colt = wave + 4 * j;
          bN[j] = *(const bf16x8*)(bBase + (size_t)colt * (16 * 512) + (kt + 1) * 32);
        }
      }
    }
    // ---- convert A to bf16 in-register, then MFMA
    bf16x8 af;
    af[0] = (short)f2bf(a0C.x); af[1] = (short)f2bf(a0C.y);
    af[2] = (short)f2bf(a0C.z); af[3] = (short)f2bf(a0C.w);
    af[4] = (short)f2bf(a1C.x); af[5] = (short)f2bf(a1C.y);
    af[6] = (short)f2bf(a1C.z); af[7] = (short)f2bf(a1C.w);
    #pragma unroll
    for (int j = 0; j < 6; ++j) {
      if (j < ntiles)
        acc[j] = __builtin_amdgcn_mfma_f32_16x16x32_bf16(af, bC[j], acc[j], 0, 0, 0);
    }
    // ---- rotate pipeline (full unroll -> pure register renames)
    a0C = a0N; a1C = a1N;
    #pragma unroll
    for (int j = 0; j < 6; ++j) {
      if (j < ntiles) bC[j] = bN[j];
    }
  }

  // ---- write logits to LDS (C/D layout: row = q*4+reg, col = rc)
  #pragma unroll
  for (int j = 0; j < 6; ++j) {
    if (j < ntiles) {
      const int colt = wave + 4 * j;
      #pragma unroll
      for (int reg = 0; reg < 4; ++reg)
        lg[q * 4 + reg][colt * 16 + rc] = acc[j][reg];
    }
  }
  __syncthreads();

  // ---- softmax epilogue: 16 rows x 16 b, one pass of 256 threads
  {
    const int r = tid >> 4, b = tid & 15;
    const int row = row0 + r;
    if (row < TT) {
      float m = -3.4e38f;
      #pragma unroll
      for (int a = 0; a < 18; ++a) m = fmaxf(m, lg[r][b * 18 + a]);
      float sum = 0.f;
      #pragma unroll
      for (int a = 0; a < 18; ++a) sum += __expf(lg[r][b * 18 + a] - m);
      int act = actions[row];
      float aprob = __expf(lg[r][b * 18 + act] - m) / sum;

      float x0 = lg[r][288 + 2 * b], x1 = lg[r][288 + 2 * b + 1];
      float mm = fmaxf(x0, x1);
      float e0 = __expf(x0 - mm), e1 = __expf(x1 - mm);
      float inv = 1.f / (e0 + e1);

      float ms = -3.4e38f;
      #pragma unroll
      for (int j = 0; j < 16; ++j) ms = fmaxf(ms, lg[r][320 + j]);
      float ssum = 0.f;
      #pragma unroll
      for (int j = 0; j < 16; ++j) ssum += __expf(lg[r][320 + j] - ms);
      float stp = __expf(lg[r][320 + b] - ms) / ssum;

      coef[(size_t)row * NB + b] = make_float4(e0 * inv, e1 * inv, stp, aprob);
    } else if (row == TT) {
      // virtual step 2048: A = I, "action" prob = stop0 prob of row T
      float x0 = lg[r][288 + 2 * b], x1 = lg[r][288 + 2 * b + 1];
      float mm = fmaxf(x0, x1);
      float e0 = __expf(x0 - mm), e1 = __expf(x1 - mm);
      coef[(size_t)TT * NB + b] = make_float4(1.f, 0.f, 0.f, e0 / (e0 + e1));
    }
  }
}

// ---------------- kernel B: pass1 — chunk transfer matrices + w-vectors ----
__global__ __launch_bounds__(64) void pass1_kernel(
    const float4* __restrict__ coef,
    float* __restrict__ Wws, float* __restrict__ Mws)
{
  const int chunk = blockIdx.x * 4 + (threadIdx.x >> 4);
  const int c = threadIdx.x & 15;
  const int i0 = chunk * CLEN + 1;

  float G[16];
  #pragma unroll
  for (int r = 0; r < 16; ++r) G[r] = (r == c) ? 1.f : 0.f;

  float4 cfA[16], cfB[16];
  #pragma unroll
  for (int r = 0; r < 16; ++r) cfA[r] = coef[(size_t)i0 * 16 + r];
  #pragma unroll
  for (int r = 0; r < 16; ++r) cfB[r] = coef[(size_t)(i0 + 1) * 16 + r];

#define P1BODY(CUR, NXT, J)                                                  \
  {                                                                          \
    if ((J) + 2 < CLEN) {                                                    \
      _Pragma("unroll")                                                      \
      for (int r = 0; r < 16; ++r)                                           \
        NXT[r] = coef[(size_t)(i0 + (J) + 2) * 16 + r];                      \
    }                                                                        \
    float ta = 0.f, tb = 0.f, tc = 0.f, td = 0.f;                            \
    _Pragma("unroll")                                                        \
    for (int r = 0; r < 4; ++r) {                                            \
      ta = fmaf(CUR[r].y,      G[r],      ta);                               \
      tb = fmaf(CUR[r + 4].y,  G[r + 4],  tb);                               \
      tc = fmaf(CUR[r + 8].y,  G[r + 8],  tc);                               \
      td = fmaf(CUR[r + 12].y, G[r + 12], td);                               \
    }                                                                        \
    float et = EPEN * ((ta + tb) + (tc + td));                               \
    _Pragma("unroll")                                                        \
    for (int r = 0; r < 16; ++r)                                             \
      G[r] = fmaf(CUR[r].x, G[r], CUR[r].z * et);                            \
    float wa = 0.f, wb = 0.f, wc = 0.f, wd = 0.f;                            \
    _Pragma("unroll")                                                        \
    for (int r = 0; r < 4; ++r) {                                            \
      wa = fmaf(CUR[r].w,      G[r],      wa);                               \
      wb = fmaf(CUR[r + 4].w,  G[r + 4],  wb);                               \
      wc = fmaf(CUR[r + 8].w,  G[r + 8],  wc);                               \
      wd = fmaf(CUR[r + 12].w, G[r + 12], wd);                               \
    }                                                                        \
    Wws[(size_t)(chunk * CLEN + (J)) * 16 + c] = (wa + wb) + (wc + wd);      \
  }

  for (int j = 0; j < CLEN; j += 2) {
    P1BODY(cfA, cfB, j);
    P1BODY(cfB, cfA, j + 1);
  }
#undef P1BODY

  #pragma unroll
  for (int r = 0; r < 16; ++r)
    Mws[chunk * 256 + r * 16 + c] = G[r];
}

// ---------------- kernel C: pass2 — sequential chunk walk + term sums -----
// 256 threads (4 waves): thread (rr, c) owns steps rr and rr+16 of each
// chunk.
template <int N>
__device__ __forceinline__ float ror_add(float v) {
  int r = __builtin_amdgcn_mov_dpp(__float_as_int(v), 0x120 + N, 0xF, 0xF, true);
  return v + __int_as_float(r);
}
__device__ __forceinline__ float reduce16(float v) {
  v = ror_add<8>(v); v = ror_add<4>(v); v = ror_add<2>(v); v = ror_add<1>(v);
  return v;
}

__global__ __launch_bounds__(256) void pass2_kernel(
    const float4* __restrict__ coef,
    const float* __restrict__ Wws, const float* __restrict__ Mws,
    float* __restrict__ out)
{
  __shared__ float lds_p[2][16];
  __shared__ float lds_acc[16];
  const int tid = threadIdx.x;
  const int rr = tid >> 4, c = tid & 15;       // rr = 0..15

  float4 c0 = coef[c];
  float p = c0.z;
  float U0 = reduce16(c0.w * p);
  float acc = (tid == 0) ? __logf(U0) : 0.f;
  int Ecum = 0;
  long long Ktot = 0;

  float wbufA[4], wbufB[4], mbuf[4];
  #pragma unroll
  for (int q = 0; q < 4; ++q) {
    wbufA[q] = Wws[(size_t)(q * CLEN + rr) * 16 + c];
    wbufB[q] = Wws[(size_t)(q * CLEN + rr + 16) * 16 + c];
    mbuf[q]  = Mws[q * 256 + rr * 16 + c];
  }

  for (int kb = 0; kb < NCHUNK; kb += 4) {
    #pragma unroll
    for (int q = 0; q < 4; ++q) {
      const int k = kb + q;
      float wa = wbufA[q], wb = wbufB[q], mc = mbuf[q];
      if (k + 4 < NCHUNK) {
        wbufA[q] = Wws[(size_t)((k + 4) * CLEN + rr) * 16 + c];
        wbufB[q] = Wws[(size_t)((k + 4) * CLEN + rr + 16) * 16 + c];
        mbuf[q]  = Mws[(k + 4) * 256 + rr * 16 + c];
      }
      float Ua = reduce16(wa * p);
      float Ub = reduce16(wb * p);
      if (c == 0) acc += __logf(Ua) + __logf(Ub);
      Ktot += 32LL * (long long)Ecum;
      float y = reduce16(mc * p);
      if (c == 0) lds_p[k & 1][rr] = y;
      __syncthreads();
      float pn = lds_p[k & 1][c];
      float p0 = lds_p[k & 1][0];
      int eb = (__float_as_int(p0) >> 23) & 255;
      Ecum += eb - 127;
      p = pn * __int_as_float((254 - eb) << 23);
    }
  }

  if (c == 0) lds_acc[rr] = acc;
  __syncthreads();
  if (tid == 0) {
    double s = 0.0;
    #pragma unroll
    for (int i = 0; i < 16; ++i) s += (double)lds_acc[i];
    out[0] = (float)(s + 0.6931471805599453 * (double)Ktot);
  }
}

extern "C" void kernel_launch(void* const* d_in, const int* in_sizes, int n_in,
                              void* d_out, int out_size, void* d_ws, size_t ws_size,
                              hipStream_t stream) {
  const float* s_i = (const float*)d_in[0];
  const float* Wa  = (const float*)d_in[1];
  const float* Ws  = (const float*)d_in[2];
  const float* Wst = (const float*)d_in[3];
  const int*   act = (const int*)d_in[4];

  char* ws = (char*)d_ws;
  float4* coef = (float4*)ws;                        //   524,544 B
  float*  Wws  = (float*)(ws + 524544);              // + 131,072 B
  float*  Mws  = (float*)(ws + 524544 + 131072);     // +  65,536 B
  ushort* Wt   = (ushort*)(ws + 524544 + 131072 + 65536);  // + 344,064 B (total ~1.04 MB)

  prep_kernel <<<672, 256, 0, stream>>>(Wa, Ws, Wst, Wt);
  proj_kernel <<<129, 256, 0, stream>>>(s_i, Wt, act, coef);
  pass1_kernel<<<16,  64,  0, stream>>>(coef, Wws, Mws);
  pass2_kernel<<<1,   256, 0, stream>>>(coef, Wws, Mws, (float*)d_out);
}

// Round 4
// 128.161 us; speedup vs baseline: 1.1710x; 1.0218x over previous
//
#include <hip/hip_runtime.h>

#define TT    2048
#define SS    512
#define NB    16
#define EPEN  0.60653065971263342f   // exp(-0.5)
#define NCHUNK 64
#define CLEN   32

typedef __attribute__((ext_vector_type(4))) float  floatx4;
typedef __attribute__((ext_vector_type(8))) short  bf16x8;

__device__ __forceinline__ ushort f2bf(float x) {   // RNE fp32 -> bf16
  unsigned u = __float_as_uint(x);
  u += 0x7fffu + ((u >> 16) & 1u);
  return (ushort)(u >> 16);
}

// ---------------- kernel 0: W -> transposed bf16  Wt[col][k] ---------------
__global__ __launch_bounds__(256) void prep_kernel(
    const float* __restrict__ Wa, const float* __restrict__ Ws,
    const float* __restrict__ Wst, ushort* __restrict__ Wt)
{
  int idx = blockIdx.x * 256 + threadIdx.x;       // 336*512 = 172032
  if (idx >= 336 * 512) return;
  int col = idx >> 9, k = idx & 511;
  float v;
  if (col < 288)      v = Wa [(size_t)k * 288 + col];
  else if (col < 320) v = Ws [(size_t)k * 32  + (col - 288)];
  else                v = Wst[(size_t)k * 16  + (col - 320)];
  Wt[idx] = f2bf(v);
}

// ---------------- kernel A: MFMA GEMM + softmax -> coef --------------------
// 129 blocks x 16 rows, 8 waves/block (512 thr). NO LDS staging, NO barrier
// in the k-loop. Wave (kh, ng): kh in {0,1} owns k-tiles kh*8..kh*8+7 (2-way
// k-split halves the serial latency chain and gives 2 waves/SIMD of TLP);
// ng in {0..3} owns n-tiles {ng, ng+4, ...} (ng 0: 6 tiles, else 5).
// Partial sums merge through the lg LDS buffer: kh=0 writes, kh=1 adds.
__global__ __launch_bounds__(512) void proj_kernel(
    const float* __restrict__ s_i,
    const ushort* __restrict__ Wt,
    const int*   __restrict__ actions,
    float4*      __restrict__ coef)
{
  __shared__ float lg[16][346];    // stride 346: 2-way bank aliasing (free)

  const int tid  = threadIdx.x;
  const int wave = tid >> 6, lane = tid & 63;
  const int q = lane >> 4, rc = lane & 15;
  const int row0 = blockIdx.x * 16;

  const int kh = wave >> 2;                  // k-half
  const int ng = wave & 3;                   // n-group
  const int ntiles = (ng == 0) ? 6 : 5;
  const int kt0 = kh * 8;

  int arow = row0 + rc; if (arow > TT) arow = TT;
  const float*  aRow  = s_i + (size_t)arow * SS + q * 8;
  const ushort* bBase = Wt + (size_t)rc * 512 + q * 8;

  floatx4 acc[6];
  #pragma unroll
  for (int j = 0; j < 6; ++j) acc[j] = (floatx4)(0.f);

  float4 a0C, a1C, a0N, a1N;
  bf16x8 bC[6], bN[6];

  // ---- prologue: load k-tile kt0 fragments
  a0C = *(const float4*)(aRow + kt0 * 32);
  a1C = *(const float4*)(aRow + kt0 * 32 + 4);
  #pragma unroll
  for (int j = 0; j < 6; ++j) {
    if (j < ntiles) {
      const int colt = ng + 4 * j;
      bC[j] = *(const bf16x8*)(bBase + (size_t)colt * (16 * 512) + kt0 * 32);
    }
  }

  #pragma unroll
  for (int kk = 0; kk < 8; ++kk) {
    const int kt = kt0 + kk;
    // ---- issue next k-tile's loads (stay in flight under the MFMAs)
    if (kk < 7) {
      a0N = *(const float4*)(aRow + (kt + 1) * 32);
      a1N = *(const float4*)(aRow + (kt + 1) * 32 + 4);
      #pragma unroll
      for (int j = 0; j < 6; ++j) {
        if (j < ntiles) {
          const int colt = ng + 4 * j;
          bN[j] = *(const bf16x8*)(bBase + (size_t)colt * (16 * 512) + (kt + 1) * 32);
        }
      }
    }
    // ---- convert A to bf16 in-register, then MFMA
    bf16x8 af;
    af[0] = (short)f2bf(a0C.x); af[1] = (short)f2bf(a0C.y);
    af[2] = (short)f2bf(a0C.z); af[3] = (short)f2bf(a0C.w);
    af[4] = (short)f2bf(a1C.x); af[5] = (short)f2bf(a1C.y);
    af[6] = (short)f2bf(a1C.z); af[7] = (short)f2bf(a1C.w);
    #pragma unroll
    for (int j = 0; j < 6; ++j) {
      if (j < ntiles)
        acc[j] = __builtin_amdgcn_mfma_f32_16x16x32_bf16(af, bC[j], acc[j], 0, 0, 0);
    }
    // ---- rotate pipeline (full unroll -> pure register renames)
    a0C = a0N; a1C = a1N;
    #pragma unroll
    for (int j = 0; j < 6; ++j) {
      if (j < ntiles) bC[j] = bN[j];
    }
  }

  // ---- merge k-halves through LDS (C/D layout: row = q*4+reg, col = rc)
  if (kh == 0) {
    #pragma unroll
    for (int j = 0; j < 6; ++j) {
      if (j < ntiles) {
        const int colt = ng + 4 * j;
        #pragma unroll
        for (int reg = 0; reg < 4; ++reg)
          lg[q * 4 + reg][colt * 16 + rc] = acc[j][reg];
      }
    }
  }
  __syncthreads();
  if (kh == 1) {
    #pragma unroll
    for (int j = 0; j < 6; ++j) {
      if (j < ntiles) {
        const int colt = ng + 4 * j;
        #pragma unroll
        for (int reg = 0; reg < 4; ++reg)
          lg[q * 4 + reg][colt * 16 + rc] += acc[j][reg];
      }
    }
  }
  __syncthreads();

  // ---- softmax epilogue: 16 rows x 16 b, threads 0..255
  if (tid < 256) {
    const int r = tid >> 4, b = tid & 15;
    const int row = row0 + r;
    if (row < TT) {
      float m = -3.4e38f;
      #pragma unroll
      for (int a = 0; a < 18; ++a) m = fmaxf(m, lg[r][b * 18 + a]);
      float sum = 0.f;
      #pragma unroll
      for (int a = 0; a < 18; ++a) sum += __expf(lg[r][b * 18 + a] - m);
      int act = actions[row];
      float aprob = __expf(lg[r][b * 18 + act] - m) / sum;

      float x0 = lg[r][288 + 2 * b], x1 = lg[r][288 + 2 * b + 1];
      float mm = fmaxf(x0, x1);
      float e0 = __expf(x0 - mm), e1 = __expf(x1 - mm);
      float inv = 1.f / (e0 + e1);

      float ms = -3.4e38f;
      #pragma unroll
      for (int j = 0; j < 16; ++j) ms = fmaxf(ms, lg[r][320 + j]);
      float ssum = 0.f;
      #pragma unroll
      for (int j = 0; j < 16; ++j) ssum += __expf(lg[r][320 + j] - ms);
      float stp = __expf(lg[r][320 + b] - ms) / ssum;

      coef[(size_t)row * NB + b] = make_float4(e0 * inv, e1 * inv, stp, aprob);
    } else if (row == TT) {
      // virtual step 2048: A = I, "action" prob = stop0 prob of row T
      float x0 = lg[r][288 + 2 * b], x1 = lg[r][288 + 2 * b + 1];
      float mm = fmaxf(x0, x1);
      float e0 = __expf(x0 - mm), e1 = __expf(x1 - mm);
      coef[(size_t)TT * NB + b] = make_float4(1.f, 0.f, 0.f, e0 / (e0 + e1));
    }
  }
}

// ---------------- kernel B: pass1 — chunk transfer matrices + w-vectors ----
__global__ __launch_bounds__(64) void pass1_kernel(
    const float4* __restrict__ coef,
    float* __restrict__ Wws, float* __restrict__ Mws)
{
  const int chunk = blockIdx.x * 4 + (threadIdx.x >> 4);
  const int c = threadIdx.x & 15;
  const int i0 = chunk * CLEN + 1;

  float G[16];
  #pragma unroll
  for (int r = 0; r < 16; ++r) G[r] = (r == c) ? 1.f : 0.f;

  float4 cfA[16], cfB[16];
  #pragma unroll
  for (int r = 0; r < 16; ++r) cfA[r] = coef[(size_t)i0 * 16 + r];
  #pragma unroll
  for (int r = 0; r < 16; ++r) cfB[r] = coef[(size_t)(i0 + 1) * 16 + r];

#define P1BODY(CUR, NXT, J)                                                  \
  {                                                                          \
    if ((J) + 2 < CLEN) {                                                    \
      _Pragma("unroll")                                                      \
      for (int r = 0; r < 16; ++r)                                           \
        NXT[r] = coef[(size_t)(i0 + (J) + 2) * 16 + r];                      \
    }                                                                        \
    float ta = 0.f, tb = 0.f, tc = 0.f, td = 0.f;                            \
    _Pragma("unroll")                                                        \
    for (int r = 0; r < 4; ++r) {                                            \
      ta = fmaf(CUR[r].y,      G[r],      ta);                               \
      tb = fmaf(CUR[r + 4].y,  G[r + 4],  tb);                               \
      tc = fmaf(CUR[r + 8].y,  G[r + 8],  tc);                               \
      td = fmaf(CUR[r + 12].y, G[r + 12], td);                               \
    }                                                                        \
    float et = EPEN * ((ta + tb) + (tc + td));                               \
    _Pragma("unroll")                                                        \
    for (int r = 0; r < 16; ++r)                                             \
      G[r] = fmaf(CUR[r].x, G[r], CUR[r].z * et);                            \
    float wa = 0.f, wb = 0.f, wc = 0.f, wd = 0.f;                            \
    _Pragma("unroll")                                                        \
    for (int r = 0; r < 4; ++r) {                                            \
      wa = fmaf(CUR[r].w,      G[r],      wa);                               \
      wb = fmaf(CUR[r + 4].w,  G[r + 4],  wb);                               \
      wc = fmaf(CUR[r + 8].w,  G[r + 8],  wc);                               \
      wd = fmaf(CUR[r + 12].w, G[r + 12], wd);                               \
    }                                                                        \
    Wws[(size_t)(chunk * CLEN + (J)) * 16 + c] = (wa + wb) + (wc + wd);      \
  }

  for (int j = 0; j < CLEN; j += 2) {
    P1BODY(cfA, cfB, j);
    P1BODY(cfB, cfA, j + 1);
  }
#undef P1BODY

  #pragma unroll
  for (int r = 0; r < 16; ++r)
    Mws[chunk * 256 + r * 16 + c] = G[r];
}

// ---------------- kernel C: pass2 — sequential chunk walk + term sums -----
// 256 threads (4 waves): thread (rr, c) owns steps rr and rr+16 of each
// chunk.
template <int N>
__device__ __forceinline__ float ror_add(float v) {
  int r = __builtin_amdgcn_mov_dpp(__float_as_int(v), 0x120 + N, 0xF, 0xF, true);
  return v + __int_as_float(r);
}
__device__ __forceinline__ float reduce16(float v) {
  v = ror_add<8>(v); v = ror_add<4>(v); v = ror_add<2>(v); v = ror_add<1>(v);
  return v;
}

__global__ __launch_bounds__(256) void pass2_kernel(
    const float4* __restrict__ coef,
    const float* __restrict__ Wws, const float* __restrict__ Mws,
    float* __restrict__ out)
{
  __shared__ float lds_p[2][16];
  __shared__ float lds_acc[16];
  const int tid = threadIdx.x;
  const int rr = tid >> 4, c = tid & 15;       // rr = 0..15

  float4 c0 = coef[c];
  float p = c0.z;
  float U0 = reduce16(c0.w * p);
  float acc = (tid == 0) ? __logf(U0) : 0.f;
  int Ecum = 0;
  long long Ktot = 0;

  float wbufA[4], wbufB[4], mbuf[4];
  #pragma unroll
  for (int q = 0; q < 4; ++q) {
    wbufA[q] = Wws[(size_t)(q * CLEN + rr) * 16 + c];
    wbufB[q] = Wws[(size_t)(q * CLEN + rr + 16) * 16 + c];
    mbuf[q]  = Mws[q * 256 + rr * 16 + c];
  }

  for (int kb = 0; kb < NCHUNK; kb += 4) {
    #pragma unroll
    for (int q = 0; q < 4; ++q) {
      const int k = kb + q;
      float wa = wbufA[q], wb = wbufB[q], mc = mbuf[q];
      if (k + 4 < NCHUNK) {
        wbufA[q] = Wws[(size_t)((k + 4) * CLEN + rr) * 16 + c];
        wbufB[q] = Wws[(size_t)((k + 4) * CLEN + rr + 16) * 16 + c];
        mbuf[q]  = Mws[(k + 4) * 256 + rr * 16 + c];
      }
      float Ua = reduce16(wa * p);
      float Ub = reduce16(wb * p);
      if (c == 0) acc += __logf(Ua) + __logf(Ub);
      Ktot += 32LL * (long long)Ecum;
      float y = reduce16(mc * p);
      if (c == 0) lds_p[k & 1][rr] = y;
      __syncthreads();
      float pn = lds_p[k & 1][c];
      float p0 = lds_p[k & 1][0];
      int eb = (__float_as_int(p0) >> 23) & 255;
      Ecum += eb - 127;
      p = pn * __int_as_float((254 - eb) << 23);
    }
  }

  if (c == 0) lds_acc[rr] = acc;
  __syncthreads();
  if (tid == 0) {
    double s = 0.0;
    #pragma unroll
    for (int i = 0; i < 16; ++i) s += (double)lds_acc[i];
    out[0] = (float)(s + 0.6931471805599453 * (double)Ktot);
  }
}

extern "C" void kernel_launch(void* const* d_in, const int* in_sizes, int n_in,
                              void* d_out, int out_size, void* d_ws, size_t ws_size,
                              hipStream_t stream) {
  const float* s_i = (const float*)d_in[0];
  const float* Wa  = (const float*)d_in[1];
  const float* Ws  = (const float*)d_in[2];
  const float* Wst = (const float*)d_in[3];
  const int*   act = (const int*)d_in[4];

  char* ws = (char*)d_ws;
  float4* coef = (float4*)ws;                        //   524,544 B
  float*  Wws  = (float*)(ws + 524544);              // + 131,072 B
  float*  Mws  = (float*)(ws + 524544 + 131072);     // +  65,536 B
  ushort* Wt   = (ushort*)(ws + 524544 + 131072 + 65536);  // + 344,064 B (total ~1.04 MB)

  prep_kernel <<<672, 256, 0, stream>>>(Wa, Ws, Wst, Wt);
  proj_kernel <<<129, 512, 0, stream>>>(s_i, Wt, act, coef);
  pass1_kernel<<<16,  64,  0, stream>>>(coef, Wws, Mws);
  pass2_kernel<<<1,   256, 0, stream>>>(coef, Wws, Mws, (float*)d_out);
}

// Round 5
// 115.104 us; speedup vs baseline: 1.3038x; 1.1134x over previous
//
#include <hip/hip_runtime.h>

#define TT    2048
#define SS    512
#define NB    16
#define EPEN  0.60653065971263342f   // exp(-0.5)
#define NCHUNK 64
#define CLEN   32

typedef __attribute__((ext_vector_type(4))) float  floatx4;
typedef __attribute__((ext_vector_type(8))) short  bf16x8;

__device__ __forceinline__ ushort f2bf(float x) {   // RNE fp32 -> bf16
  unsigned u = __float_as_uint(x);
  u += 0x7fffu + ((u >> 16) & 1u);
  return (ushort)(u >> 16);
}

// ---------------- kernel 0: W -> transposed bf16  Wt[col][k] ---------------
__global__ __launch_bounds__(256) void prep_kernel(
    const float* __restrict__ Wa, const float* __restrict__ Ws,
    const float* __restrict__ Wst, ushort* __restrict__ Wt)
{
  int idx = blockIdx.x * 256 + threadIdx.x;       // 336*512 = 172032
  if (idx >= 336 * 512) return;
  int col = idx >> 9, k = idx & 511;
  float v;
  if (col < 288)      v = Wa [(size_t)k * 288 + col];
  else if (col < 320) v = Ws [(size_t)k * 32  + (col - 288)];
  else                v = Wst[(size_t)k * 16  + (col - 320)];
  Wt[idx] = f2bf(v);
}

// ---------------- kernel A: MFMA GEMM + softmax -> coef --------------------
// 129 blocks x 16 rows, 8 waves/block (512 thr). NO LDS staging, NO barrier
// in the k-loop. Wave (kh, ng): kh in {0,1} owns k-tiles kh*8..kh*8+7 (2-way
// k-split halves the serial latency chain and gives 2 waves/SIMD of TLP);
// ng in {0..3} owns n-tiles {ng, ng+4, ...} (ng 0: 6 tiles, else 5).
// Partial sums merge through the lg LDS buffer: kh=0 writes, kh=1 adds.
__global__ __launch_bounds__(512) void proj_kernel(
    const float* __restrict__ s_i,
    const ushort* __restrict__ Wt,
    const int*   __restrict__ actions,
    float4*      __restrict__ coef)
{
  __shared__ float lg[16][346];    // stride 346: 2-way bank aliasing (free)

  const int tid  = threadIdx.x;
  const int wave = tid >> 6, lane = tid & 63;
  const int q = lane >> 4, rc = lane & 15;
  const int row0 = blockIdx.x * 16;

  const int kh = wave >> 2;                  // k-half
  const int ng = wave & 3;                   // n-group
  const int ntiles = (ng == 0) ? 6 : 5;
  const int kt0 = kh * 8;

  int arow = row0 + rc; if (arow > TT) arow = TT;
  const float*  aRow  = s_i + (size_t)arow * SS + q * 8;
  const ushort* bBase = Wt + (size_t)rc * 512 + q * 8;

  floatx4 acc[6];
  #pragma unroll
  for (int j = 0; j < 6; ++j) acc[j] = (floatx4)(0.f);

  float4 a0C, a1C, a0N, a1N;
  bf16x8 bC[6], bN[6];

  // ---- prologue: load k-tile kt0 fragments
  a0C = *(const float4*)(aRow + kt0 * 32);
  a1C = *(const float4*)(aRow + kt0 * 32 + 4);
  #pragma unroll
  for (int j = 0; j < 6; ++j) {
    if (j < ntiles) {
      const int colt = ng + 4 * j;
      bC[j] = *(const bf16x8*)(bBase + (size_t)colt * (16 * 512) + kt0 * 32);
    }
  }

  #pragma unroll
  for (int kk = 0; kk < 8; ++kk) {
    const int kt = kt0 + kk;
    // ---- issue next k-tile's loads (stay in flight under the MFMAs)
    if (kk < 7) {
      a0N = *(const float4*)(aRow + (kt + 1) * 32);
      a1N = *(const float4*)(aRow + (kt + 1) * 32 + 4);
      #pragma unroll
      for (int j = 0; j < 6; ++j) {
        if (j < ntiles) {
          const int colt = ng + 4 * j;
          bN[j] = *(const bf16x8*)(bBase + (size_t)colt * (16 * 512) + (kt + 1) * 32);
        }
      }
    }
    // ---- convert A to bf16 in-register, then MFMA
    bf16x8 af;
    af[0] = (short)f2bf(a0C.x); af[1] = (short)f2bf(a0C.y);
    af[2] = (short)f2bf(a0C.z); af[3] = (short)f2bf(a0C.w);
    af[4] = (short)f2bf(a1C.x); af[5] = (short)f2bf(a1C.y);
    af[6] = (short)f2bf(a1C.z); af[7] = (short)f2bf(a1C.w);
    #pragma unroll
    for (int j = 0; j < 6; ++j) {
      if (j < ntiles)
        acc[j] = __builtin_amdgcn_mfma_f32_16x16x32_bf16(af, bC[j], acc[j], 0, 0, 0);
    }
    // ---- rotate pipeline (full unroll -> pure register renames)
    a0C = a0N; a1C = a1N;
    #pragma unroll
    for (int j = 0; j < 6; ++j) {
      if (j < ntiles) bC[j] = bN[j];
    }
  }

  // ---- merge k-halves through LDS (C/D layout: row = q*4+reg, col = rc)
  if (kh == 0) {
    #pragma unroll
    for (int j = 0; j < 6; ++j) {
      if (j < ntiles) {
        const int colt = ng + 4 * j;
        #pragma unroll
        for (int reg = 0; reg < 4; ++reg)
          lg[q * 4 + reg][colt * 16 + rc] = acc[j][reg];
      }
    }
  }
  __syncthreads();
  if (kh == 1) {
    #pragma unroll
    for (int j = 0; j < 6; ++j) {
      if (j < ntiles) {
        const int colt = ng + 4 * j;
        #pragma unroll
        for (int reg = 0; reg < 4; ++reg)
          lg[q * 4 + reg][colt * 16 + rc] += acc[j][reg];
      }
    }
  }
  __syncthreads();

  // ---- softmax epilogue: 16 rows x 16 b, threads 0..255
  if (tid < 256) {
    const int r = tid >> 4, b = tid & 15;
    const int row = row0 + r;
    if (row < TT) {
      float m = -3.4e38f;
      #pragma unroll
      for (int a = 0; a < 18; ++a) m = fmaxf(m, lg[r][b * 18 + a]);
      float sum = 0.f;
      #pragma unroll
      for (int a = 0; a < 18; ++a) sum += __expf(lg[r][b * 18 + a] - m);
      int act = actions[row];
      float aprob = __expf(lg[r][b * 18 + act] - m) / sum;

      float x0 = lg[r][288 + 2 * b], x1 = lg[r][288 + 2 * b + 1];
      float mm = fmaxf(x0, x1);
      float e0 = __expf(x0 - mm), e1 = __expf(x1 - mm);
      float inv = 1.f / (e0 + e1);

      float ms = -3.4e38f;
      #pragma unroll
      for (int j = 0; j < 16; ++j) ms = fmaxf(ms, lg[r][320 + j]);
      float ssum = 0.f;
      #pragma unroll
      for (int j = 0; j < 16; ++j) ssum += __expf(lg[r][320 + j] - ms);
      float stp = __expf(lg[r][320 + b] - ms) / ssum;

      coef[(size_t)row * NB + b] = make_float4(e0 * inv, e1 * inv, stp, aprob);
    } else if (row == TT) {
      // virtual step 2048: A = I, "action" prob = stop0 prob of row T
      float x0 = lg[r][288 + 2 * b], x1 = lg[r][288 + 2 * b + 1];
      float mm = fmaxf(x0, x1);
      float e0 = __expf(x0 - mm), e1 = __expf(x1 - mm);
      coef[(size_t)TT * NB + b] = make_float4(1.f, 0.f, 0.f, e0 / (e0 + e1));
    }
  }
}

// ---------------- kernel B: pass1 — chunk transfer matrices + w-vectors ----
__global__ __launch_bounds__(64) void pass1_kernel(
    const float4* __restrict__ coef,
    float* __restrict__ Wws, float* __restrict__ Mws)
{
  const int chunk = blockIdx.x * 4 + (threadIdx.x >> 4);
  const int c = threadIdx.x & 15;
  const int i0 = chunk * CLEN + 1;

  float G[16];
  #pragma unroll
  for (int r = 0; r < 16; ++r) G[r] = (r == c) ? 1.f : 0.f;

  float4 cfA[16], cfB[16];
  #pragma unroll
  for (int r = 0; r < 16; ++r) cfA[r] = coef[(size_t)i0 * 16 + r];
  #pragma unroll
  for (int r = 0; r < 16; ++r) cfB[r] = coef[(size_t)(i0 + 1) * 16 + r];

#define P1BODY(CUR, NXT, J)                                                  \
  {                                                                          \
    if ((J) + 2 < CLEN) {                                                    \
      _Pragma("unroll")                                                      \
      for (int r = 0; r < 16; ++r)                                           \
        NXT[r] = coef[(size_t)(i0 + (J) + 2) * 16 + r];                      \
    }                                                                        \
    float ta = 0.f, tb = 0.f, tc = 0.f, td = 0.f;                            \
    _Pragma("unroll")                                                        \
    for (int r = 0; r < 4; ++r) {                                            \
      ta = fmaf(CUR[r].y,      G[r],      ta);                               \
      tb = fmaf(CUR[r + 4].y,  G[r + 4],  tb);                               \
      tc = fmaf(CUR[r + 8].y,  G[r + 8],  tc);                               \
      td = fmaf(CUR[r + 12].y, G[r + 12], td);                               \
    }                                                                        \
    float et = EPEN * ((ta + tb) + (tc + td));                               \
    _Pragma("unroll")                                                        \
    for (int r = 0; r < 16; ++r)                                             \
      G[r] = fmaf(CUR[r].x, G[r], CUR[r].z * et);                            \
    float wa = 0.f, wb = 0.f, wc = 0.f, wd = 0.f;                            \
    _Pragma("unroll")                                                        \
    for (int r = 0; r < 4; ++r) {                                            \
      wa = fmaf(CUR[r].w,      G[r],      wa);                               \
      wb = fmaf(CUR[r + 4].w,  G[r + 4],  wb);                               \
      wc = fmaf(CUR[r + 8].w,  G[r + 8],  wc);                               \
      wd = fmaf(CUR[r + 12].w, G[r + 12], wd);                               \
    }                                                                        \
    Wws[(size_t)(chunk * CLEN + (J)) * 16 + c] = (wa + wb) + (wc + wd);      \
  }

  for (int j = 0; j < CLEN; j += 2) {
    P1BODY(cfA, cfB, j);
    P1BODY(cfB, cfA, j + 1);
  }
#undef P1BODY

  #pragma unroll
  for (int r = 0; r < 16; ++r)
    Mws[chunk * 256 + r * 16 + c] = G[r];
}

// ---------------- kernel C: pass2 — two-phase chunk walk ------------------
// Phase 1 (wave 0 only): serial 16x16 matvec chain across 64 chunks, fully
// in-wave (no barrier, no LDS round-trip). Lane l = (g = l>>4, r = l&15)
// holds M[r][4g..4g+3] (coalesced float4, prefetched 2 chunks deep) and
// p[4g..4g+3]. Per chunk: 4 FMA -> xor16 swizzle-add -> xor32 shfl-add
// (y_r in lane) -> bpermute gather of new p + p0 exponent -> rescale.
// Chunk-start scaled p vectors are saved to LDS; exact exponent bookkeeping
// (Ktot) stays in thread 0's registers (bit-identical to old scheme).
// Phase 2 (all 512 threads): the 2048 log(w_j . p_chunk) terms in parallel
// (4 per thread), shuffle-reduced; thread 0 adds ln2*Ktot + U0 term.
__global__ __launch_bounds__(512) void pass2_kernel(
    const float4* __restrict__ coef,
    const float* __restrict__ Wws, const float* __restrict__ Mws,
    float* __restrict__ out)
{
  __shared__ float pbuf[NCHUNK][16];   // chunk-start scaled p vectors
  __shared__ float wacc[8];            // per-wave partial log sums

  const int tid = threadIdx.x;
  long long Ktot = 0;                  // only thread 0's value is used

  // ---------------- phase 1: serial chain, wave 0 only ----------------
  if (tid < 64) {
    const int r = tid & 15, g = tid >> 4;
    // initial p: p[c] = coef[c].z  (row 0 stop prob)
    float pj0 = coef[4 * g + 0].z;
    float pj1 = coef[4 * g + 1].z;
    float pj2 = coef[4 * g + 2].z;
    float pj3 = coef[4 * g + 3].z;

    const int moff = r * 16 + 4 * g;
    float4 mA = *(const float4*)&Mws[moff];          // chunk 0
    float4 mB = *(const float4*)&Mws[256 + moff];    // chunk 1
    int Ecum = 0;

    for (int k = 0; k < NCHUNK; ++k) {
      // save chunk-start scaled p (4 lanes with r==0 cover the 16 entries)
      if (r == 0) *(float4*)&pbuf[k][4 * g] = make_float4(pj0, pj1, pj2, pj3);
      Ktot += 32LL * (long long)Ecum;

      float4 m = (k & 1) ? mB : mA;
      float part = fmaf(m.x, pj0, fmaf(m.y, pj1, fmaf(m.z, pj2, m.w * pj3)));

      if (k + 2 < NCHUNK) {                          // prefetch depth 2
        float4 mn = *(const float4*)&Mws[(k + 2) * 256 + moff];
        if (k & 1) mB = mn; else mA = mn;
      }

      // reduce the 4 g-groups: xor16 within 32-lane halves, then xor32
      part += __int_as_float(
          __builtin_amdgcn_ds_swizzle(__float_as_int(part), 0x401F));
      part += __shfl_xor(part, 32, 64);
      // lane now holds y_r (replicated across g)

      float y0 = __shfl(part, 0, 64);
      float n0 = __shfl(part, 4 * g + 0, 64);
      float n1 = __shfl(part, 4 * g + 1, 64);
      float n2 = __shfl(part, 4 * g + 2, 64);
      float n3 = __shfl(part, 4 * g + 3, 64);

      int eb = (__float_as_int(y0) >> 23) & 255;
      Ecum += eb - 127;
      float sc = __int_as_float((254 - eb) << 23);
      pj0 = n0 * sc; pj1 = n1 * sc; pj2 = n2 * sc; pj3 = n3 * sc;
    }
  }
  __syncthreads();

  // ---------------- phase 2: 2048 parallel log terms ----------------
  const int j0 = tid * 4;              // 4 consecutive steps, same chunk
  const int chunk = j0 >> 5;
  float p[16];
  #pragma unroll
  for (int c = 0; c < 16; ++c) p[c] = pbuf[chunk][c];

  float lacc = 0.f;
  #pragma unroll
  for (int jj = 0; jj < 4; ++jj) {
    const float* w = Wws + (size_t)(j0 + jj) * 16;
    float4 w0 = *(const float4*)(w);
    float4 w1 = *(const float4*)(w + 4);
    float4 w2 = *(const float4*)(w + 8);
    float4 w3 = *(const float4*)(w + 12);
    float s0 = fmaf(w0.x, p[0],  fmaf(w0.y, p[1],  fmaf(w0.z, p[2],  w0.w * p[3])));
    float s1 = fmaf(w1.x, p[4],  fmaf(w1.y, p[5],  fmaf(w1.z, p[6],  w1.w * p[7])));
    float s2 = fmaf(w2.x, p[8],  fmaf(w2.y, p[9],  fmaf(w2.z, p[10], w2.w * p[11])));
    float s3 = fmaf(w3.x, p[12], fmaf(w3.y, p[13], fmaf(w3.z, p[14], w3.w * p[15])));
    lacc += __logf((s0 + s1) + (s2 + s3));
  }

  if (tid == 0) {          // U0 term: sum_c coef[c].w * coef[c].z
    float U0 = 0.f;
    #pragma unroll
    for (int c = 0; c < 16; ++c) U0 = fmaf(coef[c].w, coef[c].z, U0);
    lacc += __logf(U0);
  }

  // wave reduce, then 8-entry double sum
  lacc += __shfl_xor(lacc, 1, 64);
  lacc += __shfl_xor(lacc, 2, 64);
  lacc += __shfl_xor(lacc, 4, 64);
  lacc += __shfl_xor(lacc, 8, 64);
  lacc += __shfl_xor(lacc, 16, 64);
  lacc += __shfl_xor(lacc, 32, 64);
  if ((tid & 63) == 0) wacc[tid >> 6] = lacc;
  __syncthreads();
  if (tid == 0) {
    double s = 0.0;
    #pragma unroll
    for (int i = 0; i < 8; ++i) s += (double)wacc[i];
    out[0] = (float)(s + 0.6931471805599453 * (double)Ktot);
  }
}

extern "C" void kernel_launch(void* const* d_in, const int* in_sizes, int n_in,
                              void* d_out, int out_size, void* d_ws, size_t ws_size,
                              hipStream_t stream) {
  const float* s_i = (const float*)d_in[0];
  const float* Wa  = (const float*)d_in[1];
  const float* Ws  = (const float*)d_in[2];
  const float* Wst = (const float*)d_in[3];
  const int*   act = (const int*)d_in[4];

  char* ws = (char*)d_ws;
  float4* coef = (float4*)ws;                        //   524,544 B
  float*  Wws  = (float*)(ws + 524544);              // + 131,072 B
  float*  Mws  = (float*)(ws + 524544 + 131072);     // +  65,536 B
  ushort* Wt   = (ushort*)(ws + 524544 + 131072 + 65536);  // + 344,064 B (total ~1.04 MB)

  prep_kernel <<<672, 256, 0, stream>>>(Wa, Ws, Wst, Wt);
  proj_kernel <<<129, 512, 0, stream>>>(s_i, Wt, act, coef);
  pass1_kernel<<<16,  64,  0, stream>>>(coef, Wws, Mws);
  pass2_kernel<<<1,   512, 0, stream>>>(coef, Wws, Mws, (float*)d_out);
}

// Round 6
// 106.658 us; speedup vs baseline: 1.4071x; 1.0792x over previous
//
#include <hip/hip_runtime.h>

#define TT    2048
#define SS    512
#define NB    16
#define EPEN  0.60653065971263342f   // exp(-0.5)
#define NCHUNK 64
#define CLEN   32

typedef __attribute__((ext_vector_type(4))) float  floatx4;
typedef __attribute__((ext_vector_type(8))) short  bf16x8;

__device__ __forceinline__ ushort f2bf(float x) {   // RNE fp32 -> bf16
  unsigned u = __float_as_uint(x);
  u += 0x7fffu + ((u >> 16) & 1u);
  return (ushort)(u >> 16);
}

// ---------------- kernel 0: W -> transposed bf16  Wt[col][k] ---------------
__global__ __launch_bounds__(256) void prep_kernel(
    const float* __restrict__ Wa, const float* __restrict__ Ws,
    const float* __restrict__ Wst, ushort* __restrict__ Wt)
{
  int idx = blockIdx.x * 256 + threadIdx.x;       // 336*512 = 172032
  if (idx >= 336 * 512) return;
  int col = idx >> 9, k = idx & 511;
  float v;
  if (col < 288)      v = Wa [(size_t)k * 288 + col];
  else if (col < 320) v = Ws [(size_t)k * 32  + (col - 288)];
  else                v = Wst[(size_t)k * 16  + (col - 320)];
  Wt[idx] = f2bf(v);
}

// ---------------- kernel A: MFMA GEMM + softmax -> coef --------------------
// 129 blocks x 16 rows, 8 waves/block (512 thr). NO LDS staging, NO barrier
// in the k-loop. Wave (kh, ng): kh in {0,1} owns k-tiles kh*8..kh*8+7 (2-way
// k-split halves the serial latency chain and gives 2 waves/SIMD of TLP);
// ng in {0..3} owns n-tiles {ng, ng+4, ...} (ng 0: 6 tiles, else 5).
// Partial sums merge through the lg LDS buffer: kh=0 writes, kh=1 adds.
__global__ __launch_bounds__(512) void proj_kernel(
    const float* __restrict__ s_i,
    const ushort* __restrict__ Wt,
    const int*   __restrict__ actions,
    float4*      __restrict__ coef)
{
  __shared__ float lg[16][346];    // stride 346: 2-way bank aliasing (free)

  const int tid  = threadIdx.x;
  const int wave = tid >> 6, lane = tid & 63;
  const int q = lane >> 4, rc = lane & 15;
  const int row0 = blockIdx.x * 16;

  const int kh = wave >> 2;                  // k-half
  const int ng = wave & 3;                   // n-group
  const int ntiles = (ng == 0) ? 6 : 5;
  const int kt0 = kh * 8;

  int arow = row0 + rc; if (arow > TT) arow = TT;
  const float*  aRow  = s_i + (size_t)arow * SS + q * 8;
  const ushort* bBase = Wt + (size_t)rc * 512 + q * 8;

  floatx4 acc[6];
  #pragma unroll
  for (int j = 0; j < 6; ++j) acc[j] = (floatx4)(0.f);

  float4 a0C, a1C, a0N, a1N;
  bf16x8 bC[6], bN[6];

  // ---- prologue: load k-tile kt0 fragments
  a0C = *(const float4*)(aRow + kt0 * 32);
  a1C = *(const float4*)(aRow + kt0 * 32 + 4);
  #pragma unroll
  for (int j = 0; j < 6; ++j) {
    if (j < ntiles) {
      const int colt = ng + 4 * j;
      bC[j] = *(const bf16x8*)(bBase + (size_t)colt * (16 * 512) + kt0 * 32);
    }
  }

  #pragma unroll
  for (int kk = 0; kk < 8; ++kk) {
    const int kt = kt0 + kk;
    // ---- issue next k-tile's loads (stay in flight under the MFMAs)
    if (kk < 7) {
      a0N = *(const float4*)(aRow + (kt + 1) * 32);
      a1N = *(const float4*)(aRow + (kt + 1) * 32 + 4);
      #pragma unroll
      for (int j = 0; j < 6; ++j) {
        if (j < ntiles) {
          const int colt = ng + 4 * j;
          bN[j] = *(const bf16x8*)(bBase + (size_t)colt * (16 * 512) + (kt + 1) * 32);
        }
      }
    }
    // ---- convert A to bf16 in-register, then MFMA
    bf16x8 af;
    af[0] = (short)f2bf(a0C.x); af[1] = (short)f2bf(a0C.y);
    af[2] = (short)f2bf(a0C.z); af[3] = (short)f2bf(a0C.w);
    af[4] = (short)f2bf(a1C.x); af[5] = (short)f2bf(a1C.y);
    af[6] = (short)f2bf(a1C.z); af[7] = (short)f2bf(a1C.w);
    #pragma unroll
    for (int j = 0; j < 6; ++j) {
      if (j < ntiles)
        acc[j] = __builtin_amdgcn_mfma_f32_16x16x32_bf16(af, bC[j], acc[j], 0, 0, 0);
    }
    // ---- rotate pipeline (full unroll -> pure register renames)
    a0C = a0N; a1C = a1N;
    #pragma unroll
    for (int j = 0; j < 6; ++j) {
      if (j < ntiles) bC[j] = bN[j];
    }
  }

  // ---- merge k-halves through LDS (C/D layout: row = q*4+reg, col = rc)
  if (kh == 0) {
    #pragma unroll
    for (int j = 0; j < 6; ++j) {
      if (j < ntiles) {
        const int colt = ng + 4 * j;
        #pragma unroll
        for (int reg = 0; reg < 4; ++reg)
          lg[q * 4 + reg][colt * 16 + rc] = acc[j][reg];
      }
    }
  }
  __syncthreads();
  if (kh == 1) {
    #pragma unroll
    for (int j = 0; j < 6; ++j) {
      if (j < ntiles) {
        const int colt = ng + 4 * j;
        #pragma unroll
        for (int reg = 0; reg < 4; ++reg)
          lg[q * 4 + reg][colt * 16 + rc] += acc[j][reg];
      }
    }
  }
  __syncthreads();

  // ---- softmax epilogue: 16 rows x 16 b, threads 0..255
  if (tid < 256) {
    const int r = tid >> 4, b = tid & 15;
    const int row = row0 + r;
    if (row < TT) {
      float m = -3.4e38f;
      #pragma unroll
      for (int a = 0; a < 18; ++a) m = fmaxf(m, lg[r][b * 18 + a]);
      float sum = 0.f;
      #pragma unroll
      for (int a = 0; a < 18; ++a) sum += __expf(lg[r][b * 18 + a] - m);
      int act = actions[row];
      float aprob = __expf(lg[r][b * 18 + act] - m) / sum;

      float x0 = lg[r][288 + 2 * b], x1 = lg[r][288 + 2 * b + 1];
      float mm = fmaxf(x0, x1);
      float e0 = __expf(x0 - mm), e1 = __expf(x1 - mm);
      float inv = 1.f / (e0 + e1);

      float ms = -3.4e38f;
      #pragma unroll
      for (int j = 0; j < 16; ++j) ms = fmaxf(ms, lg[r][320 + j]);
      float ssum = 0.f;
      #pragma unroll
      for (int j = 0; j < 16; ++j) ssum += __expf(lg[r][320 + j] - ms);
      float stp = __expf(lg[r][320 + b] - ms) / ssum;

      coef[(size_t)row * NB + b] = make_float4(e0 * inv, e1 * inv, stp, aprob);
    } else if (row == TT) {
      // virtual step 2048: A = I, "action" prob = stop0 prob of row T
      float x0 = lg[r][288 + 2 * b], x1 = lg[r][288 + 2 * b + 1];
      float mm = fmaxf(x0, x1);
      float e0 = __expf(x0 - mm), e1 = __expf(x1 - mm);
      coef[(size_t)TT * NB + b] = make_float4(1.f, 0.f, 0.f, e0 / (e0 + e1));
    }
  }
}

// ---------------- kernel B: pass1 — chunk transfer matrices + w-vectors ----
__global__ __launch_bounds__(64) void pass1_kernel(
    const float4* __restrict__ coef,
    float* __restrict__ Wws, float* __restrict__ Mws)
{
  const int chunk = blockIdx.x * 4 + (threadIdx.x >> 4);
  const int c = threadIdx.x & 15;
  const int i0 = chunk * CLEN + 1;

  float G[16];
  #pragma unroll
  for (int r = 0; r < 16; ++r) G[r] = (r == c) ? 1.f : 0.f;

  float4 cfA[16], cfB[16];
  #pragma unroll
  for (int r = 0; r < 16; ++r) cfA[r] = coef[(size_t)i0 * 16 + r];
  #pragma unroll
  for (int r = 0; r < 16; ++r) cfB[r] = coef[(size_t)(i0 + 1) * 16 + r];

#define P1BODY(CUR, NXT, J)                                                  \
  {                                                                          \
    if ((J) + 2 < CLEN) {                                                    \
      _Pragma("unroll")                                                      \
      for (int r = 0; r < 16; ++r)                                           \
        NXT[r] = coef[(size_t)(i0 + (J) + 2) * 16 + r];                      \
    }                                                                        \
    float ta = 0.f, tb = 0.f, tc = 0.f, td = 0.f;                            \
    _Pragma("unroll")                                                        \
    for (int r = 0; r < 4; ++r) {                                            \
      ta = fmaf(CUR[r].y,      G[r],      ta);                               \
      tb = fmaf(CUR[r + 4].y,  G[r + 4],  tb);                               \
      tc = fmaf(CUR[r + 8].y,  G[r + 8],  tc);                               \
      td = fmaf(CUR[r + 12].y, G[r + 12], td);                               \
    }                                                                        \
    float et = EPEN * ((ta + tb) + (tc + td));                               \
    _Pragma("unroll")                                                        \
    for (int r = 0; r < 16; ++r)                                             \
      G[r] = fmaf(CUR[r].x, G[r], CUR[r].z * et);                            \
    float wa = 0.f, wb = 0.f, wc = 0.f, wd = 0.f;                            \
    _Pragma("unroll")                                                        \
    for (int r = 0; r < 4; ++r) {                                            \
      wa = fmaf(CUR[r].w,      G[r],      wa);                               \
      wb = fmaf(CUR[r + 4].w,  G[r + 4],  wb);                               \
      wc = fmaf(CUR[r + 8].w,  G[r + 8],  wc);                               \
      wd = fmaf(CUR[r + 12].w, G[r + 12], wd);                               \
    }                                                                        \
    Wws[(size_t)(chunk * CLEN + (J)) * 16 + c] = (wa + wb) + (wc + wd);      \
  }

  for (int j = 0; j < CLEN; j += 2) {
    P1BODY(cfA, cfB, j);
    P1BODY(cfB, cfA, j + 1);
  }
#undef P1BODY

  #pragma unroll
  for (int r = 0; r < 16; ++r)
    Mws[chunk * 256 + r * 16 + c] = G[r];
}

// ---------------- kernel C: pass2 — two-phase chunk walk ------------------
// Phase 1 (wave 0 only): serial 16x16 matvec chain across 64 chunks, fully
// in-wave. Lane l = (g = l>>4, r = l&15) holds M[r][4g..4g+3] (coalesced
// float4, prefetch depth 8 via named regs -> covers ~900-cyc HBM latency).
// Per chunk: FMA nest -> xor16 swizzle-add -> 8 parallel ds_bpermute
// (gather BOTH half-sums for the 4 needed columns; fuses the old xor32 +
// gather steps) -> readfirstlane exponent (scalar pipe) -> rescale.
// Arithmetic pairing (P0+P1)+(P2+P3) and FMA nest identical to the
// previous passing version; exact Ktot bookkeeping unchanged.
// Phase 2 (all 512 threads): 2048 log(w_j . p_chunk) terms in parallel,
// shuffle-reduced; thread 0 adds ln2*Ktot + U0 term.
__global__ __launch_bounds__(512) void pass2_kernel(
    const float4* __restrict__ coef,
    const float* __restrict__ Wws, const float* __restrict__ Mws,
    float* __restrict__ out)
{
  __shared__ float pbuf[NCHUNK][16];   // chunk-start scaled p vectors
  __shared__ float wacc[8];            // per-wave partial log sums

  const int tid = threadIdx.x;
  long long Ktot = 0;                  // only thread 0's value is used

  // ---------------- phase 1: serial chain, wave 0 only ----------------
  if (tid < 64) {
    const int r = tid & 15, g = tid >> 4;
    // initial p: p[c] = coef[c].z  (row 0 stop prob)
    float pj0 = coef[4 * g + 0].z;
    float pj1 = coef[4 * g + 1].z;
    float pj2 = coef[4 * g + 2].z;
    float pj3 = coef[4 * g + 3].z;

    const int moff = r * 16 + 4 * g;
    // bpermute byte addrs for the 4 columns this lane needs (lower half);
    // +128 selects the upper-half (lane+32) partner.
    const int gb0 = (4 * g) * 4, gb1 = gb0 + 4, gb2 = gb0 + 8, gb3 = gb0 + 12;
    int Ecum = 0;

    // prefetch depth 8 (named regs; no runtime indexing -> no scratch)
    float4 mR0 = *(const float4*)&Mws[0 * 256 + moff];
    float4 mR1 = *(const float4*)&Mws[1 * 256 + moff];
    float4 mR2 = *(const float4*)&Mws[2 * 256 + moff];
    float4 mR3 = *(const float4*)&Mws[3 * 256 + moff];
    float4 mR4 = *(const float4*)&Mws[4 * 256 + moff];
    float4 mR5 = *(const float4*)&Mws[5 * 256 + moff];
    float4 mR6 = *(const float4*)&Mws[6 * 256 + moff];
    float4 mR7 = *(const float4*)&Mws[7 * 256 + moff];

#define P2BODY(K, MREG, KPF)                                                 \
    {                                                                        \
      if (r == 0)                                                            \
        *(float4*)&pbuf[(K)][4 * g] = make_float4(pj0, pj1, pj2, pj3);       \
      Ktot += 32LL * (long long)Ecum;                                        \
      float part = fmaf(MREG.x, pj0,                                         \
                   fmaf(MREG.y, pj1, fmaf(MREG.z, pj2, MREG.w * pj3)));      \
      if ((KPF) < NCHUNK)                                                    \
        MREG = *(const float4*)&Mws[(KPF) * 256 + moff];                     \
      part += __int_as_float(                                                \
          __builtin_amdgcn_ds_swizzle(__float_as_int(part), 0x401F));        \
      int ip = __float_as_int(part);                                         \
      float n0 = __int_as_float(__builtin_amdgcn_ds_bpermute(gb0, ip)) +     \
                 __int_as_float(__builtin_amdgcn_ds_bpermute(gb0 + 128, ip));\
      float n1 = __int_as_float(__builtin_amdgcn_ds_bpermute(gb1, ip)) +     \
                 __int_as_float(__builtin_amdgcn_ds_bpermute(gb1 + 128, ip));\
      float n2 = __int_as_float(__builtin_amdgcn_ds_bpermute(gb2, ip)) +     \
                 __int_as_float(__builtin_amdgcn_ds_bpermute(gb2 + 128, ip));\
      float n3 = __int_as_float(__builtin_amdgcn_ds_bpermute(gb3, ip)) +     \
                 __int_as_float(__builtin_amdgcn_ds_bpermute(gb3 + 128, ip));\
      int y0b = __builtin_amdgcn_readfirstlane(__float_as_int(n0));          \
      int eb = (y0b >> 23) & 255;                                            \
      Ecum += eb - 127;                                                      \
      float sc = __int_as_float((254 - eb) << 23);                           \
      pj0 = n0 * sc; pj1 = n1 * sc; pj2 = n2 * sc; pj3 = n3 * sc;            \
    }

    for (int kb = 0; kb < NCHUNK; kb += 8) {
      P2BODY(kb + 0, mR0, kb + 8);
      P2BODY(kb + 1, mR1, kb + 9);
      P2BODY(kb + 2, mR2, kb + 10);
      P2BODY(kb + 3, mR3, kb + 11);
      P2BODY(kb + 4, mR4, kb + 12);
      P2BODY(kb + 5, mR5, kb + 13);
      P2BODY(kb + 6, mR6, kb + 14);
      P2BODY(kb + 7, mR7, kb + 15);
    }
#undef P2BODY
  }
  __syncthreads();

  // ---------------- phase 2: 2048 parallel log terms ----------------
  const int j0 = tid * 4;              // 4 consecutive steps, same chunk
  const int chunk = j0 >> 5;
  float p[16];
  #pragma unroll
  for (int c = 0; c < 16; ++c) p[c] = pbuf[chunk][c];

  float lacc = 0.f;
  #pragma unroll
  for (int jj = 0; jj < 4; ++jj) {
    const float* w = Wws + (size_t)(j0 + jj) * 16;
    float4 w0 = *(const float4*)(w);
    float4 w1 = *(const float4*)(w + 4);
    float4 w2 = *(const float4*)(w + 8);
    float4 w3 = *(const float4*)(w + 12);
    float s0 = fmaf(w0.x, p[0],  fmaf(w0.y, p[1],  fmaf(w0.z, p[2],  w0.w * p[3])));
    float s1 = fmaf(w1.x, p[4],  fmaf(w1.y, p[5],  fmaf(w1.z, p[6],  w1.w * p[7])));
    float s2 = fmaf(w2.x, p[8],  fmaf(w2.y, p[9],  fmaf(w2.z, p[10], w2.w * p[11])));
    float s3 = fmaf(w3.x, p[12], fmaf(w3.y, p[13], fmaf(w3.z, p[14], w3.w * p[15])));
    lacc += __logf((s0 + s1) + (s2 + s3));
  }

  if (tid == 0) {          // U0 term: sum_c coef[c].w * coef[c].z
    float U0 = 0.f;
    #pragma unroll
    for (int c = 0; c < 16; ++c) U0 = fmaf(coef[c].w, coef[c].z, U0);
    lacc += __logf(U0);
  }

  // wave reduce, then 8-entry double sum
  lacc += __shfl_xor(lacc, 1, 64);
  lacc += __shfl_xor(lacc, 2, 64);
  lacc += __shfl_xor(lacc, 4, 64);
  lacc += __shfl_xor(lacc, 8, 64);
  lacc += __shfl_xor(lacc, 16, 64);
  lacc += __shfl_xor(lacc, 32, 64);
  if ((tid & 63) == 0) wacc[tid >> 6] = lacc;
  __syncthreads();
  if (tid == 0) {
    double s = 0.0;
    #pragma unroll
    for (int i = 0; i < 8; ++i) s += (double)wacc[i];
    out[0] = (float)(s + 0.6931471805599453 * (double)Ktot);
  }
}

extern "C" void kernel_launch(void* const* d_in, const int* in_sizes, int n_in,
                              void* d_out, int out_size, void* d_ws, size_t ws_size,
                              hipStream_t stream) {
  const float* s_i = (const float*)d_in[0];
  const float* Wa  = (const float*)d_in[1];
  const float* Ws  = (const float*)d_in[2];
  const float* Wst = (const float*)d_in[3];
  const int*   act = (const int*)d_in[4];

  char* ws = (char*)d_ws;
  float4* coef = (float4*)ws;                        //   524,544 B
  float*  Wws  = (float*)(ws + 524544);              // + 131,072 B
  float*  Mws  = (float*)(ws + 524544 + 131072);     // +  65,536 B
  ushort* Wt   = (ushort*)(ws + 524544 + 131072 + 65536);  // + 344,064 B (total ~1.04 MB)

  prep_kernel <<<672, 256, 0, stream>>>(Wa, Ws, Wst, Wt);
  proj_kernel <<<129, 512, 0, stream>>>(s_i, Wt, act, coef);
  pass1_kernel<<<16,  64,  0, stream>>>(coef, Wws, Mws);
  pass2_kernel<<<1,   512, 0, stream>>>(coef, Wws, Mws, (float*)d_out);
}

// Round 7
// 98.110 us; speedup vs baseline: 1.5297x; 1.0871x over previous
//
#include <hip/hip_runtime.h>

#define TT    2048
#define SS    512
#define NB    16
#define EPEN  0.60653065971263342f   // exp(-0.5)
#define NCHUNK 64
#define CLEN   32

typedef __attribute__((ext_vector_type(4))) float  floatx4;
typedef __attribute__((ext_vector_type(8))) short  bf16x8;

__device__ __forceinline__ ushort f2bf(float x) {   // RNE fp32 -> bf16
  unsigned u = __float_as_uint(x);
  u += 0x7fffu + ((u >> 16) & 1u);
  return (ushort)(u >> 16);
}

__device__ __forceinline__ unsigned pack2(ushort a, ushort b) {
  return (unsigned)a | ((unsigned)b << 16);
}

// ---------------- kernel 0: emit BOTH operands in MFMA-fragment order -----
// Wt2[(((colt*16+kt)*16+rc)*4+q)*8+e] = bf16(W[kt*32+q*8+e][colt*16+rc])
// Af [(((mt  *16+kt)*16+rc)*4+q)*8+e] = bf16(s_i[min(mt*16+rc,2048)][kt*32+q*8+e])
// -> every proj load is one fully-coalesced 1KB wave transaction.
__global__ __launch_bounds__(256) void prep_kernel(
    const float* __restrict__ Wa, const float* __restrict__ Ws,
    const float* __restrict__ Wst, const float* __restrict__ s_i,
    ushort* __restrict__ Wt2, ushort* __restrict__ Af)
{
  int fid = blockIdx.x * 256 + threadIdx.x;   // 21504 B-frags + 132096 A-frags
  if (fid < 21504) {
    const int q = fid & 3, rc = (fid >> 2) & 15, kt = (fid >> 6) & 15, colt = fid >> 10;
    const int col = colt * 16 + rc;
    const int kbase = kt * 32 + q * 8;
    ushort h[8];
    #pragma unroll
    for (int e = 0; e < 8; ++e) {
      const int k = kbase + e;
      float v;
      if (col < 288)      v = Wa [(size_t)k * 288 + col];
      else if (col < 320) v = Ws [(size_t)k * 32  + (col - 288)];
      else                v = Wst[(size_t)k * 16  + (col - 320)];
      h[e] = f2bf(v);
    }
    uint4 o = make_uint4(pack2(h[0], h[1]), pack2(h[2], h[3]),
                         pack2(h[4], h[5]), pack2(h[6], h[7]));
    *(uint4*)(Wt2 + (size_t)fid * 8) = o;
  } else {
    const int aid = fid - 21504;
    if (aid < 132096) {
      const int q = aid & 3, rc = (aid >> 2) & 15, kt = (aid >> 6) & 15, mt = aid >> 10;
      int row = mt * 16 + rc; if (row > TT) row = TT;
      const float* src = s_i + (size_t)row * SS + kt * 32 + q * 8;
      float4 v0 = *(const float4*)src;
      float4 v1 = *(const float4*)(src + 4);
      uint4 o = make_uint4(pack2(f2bf(v0.x), f2bf(v0.y)),
                           pack2(f2bf(v0.z), f2bf(v0.w)),
                           pack2(f2bf(v1.x), f2bf(v1.y)),
                           pack2(f2bf(v1.z), f2bf(v1.w)));
      *(uint4*)(Af + (size_t)aid * 8) = o;
    }
  }
}

// ---------------- kernel A: MFMA GEMM + softmax -> coef --------------------
// 129 blocks x 16 rows, 8 waves (512 thr). All loads are pre-laid-out
// fragments (1KB coalesced per wave load, zero in-loop conversion).
// Wave (kh, ng): kh owns k-tiles kh*8.., ng owns n-tiles {ng, ng+4, ...}.
// 1-deep software pipeline, no barrier in the k-loop; k-halves merge in LDS.
__global__ __launch_bounds__(512) void proj_kernel(
    const ushort* __restrict__ Af,
    const ushort* __restrict__ Wt2,
    const int*   __restrict__ actions,
    float4*      __restrict__ coef)
{
  __shared__ float lg[16][346];    // stride 346: 2-way bank aliasing (free)

  const int tid  = threadIdx.x;
  const int wave = tid >> 6, lane = tid & 63;
  const int q = lane >> 4, rc = lane & 15;
  const int row0 = blockIdx.x * 16;

  const int kh = wave >> 2;                  // k-half
  const int ng = wave & 3;                   // n-group
  const int ntiles = (ng == 0) ? 6 : 5;
  const int kt0 = kh * 8;

  const ushort* aBase = Af  + (size_t)blockIdx.x * 8192 + rc * 32 + q * 8;
  const ushort* bBase = Wt2 + rc * 32 + q * 8;

  floatx4 acc[6];
  #pragma unroll
  for (int j = 0; j < 6; ++j) acc[j] = (floatx4)(0.f);

  bf16x8 aC, aN, bC[6], bN[6];

  // ---- prologue: load k-tile kt0 fragments
  aC = *(const bf16x8*)(aBase + kt0 * 512);
  #pragma unroll
  for (int j = 0; j < 6; ++j) {
    if (j < ntiles) {
      const int colt = ng + 4 * j;
      bC[j] = *(const bf16x8*)(bBase + (size_t)colt * 8192 + kt0 * 512);
    }
  }

  #pragma unroll
  for (int kk = 0; kk < 8; ++kk) {
    const int kt = kt0 + kk;
    // ---- issue next k-tile's loads (stay in flight under the MFMAs)
    if (kk < 7) {
      aN = *(const bf16x8*)(aBase + (kt + 1) * 512);
      #pragma unroll
      for (int j = 0; j < 6; ++j) {
        if (j < ntiles) {
          const int colt = ng + 4 * j;
          bN[j] = *(const bf16x8*)(bBase + (size_t)colt * 8192 + (kt + 1) * 512);
        }
      }
    }
    #pragma unroll
    for (int j = 0; j < 6; ++j) {
      if (j < ntiles)
        acc[j] = __builtin_amdgcn_mfma_f32_16x16x32_bf16(aC, bC[j], acc[j], 0, 0, 0);
    }
    // ---- rotate pipeline (full unroll -> pure register renames)
    aC = aN;
    #pragma unroll
    for (int j = 0; j < 6; ++j) {
      if (j < ntiles) bC[j] = bN[j];
    }
  }

  // ---- merge k-halves through LDS (C/D layout: row = q*4+reg, col = rc)
  if (kh == 0) {
    #pragma unroll
    for (int j = 0; j < 6; ++j) {
      if (j < ntiles) {
        const int colt = ng + 4 * j;
        #pragma unroll
        for (int reg = 0; reg < 4; ++reg)
          lg[q * 4 + reg][colt * 16 + rc] = acc[j][reg];
      }
    }
  }
  __syncthreads();
  if (kh == 1) {
    #pragma unroll
    for (int j = 0; j < 6; ++j) {
      if (j < ntiles) {
        const int colt = ng + 4 * j;
        #pragma unroll
        for (int reg = 0; reg < 4; ++reg)
          lg[q * 4 + reg][colt * 16 + rc] += acc[j][reg];
      }
    }
  }
  __syncthreads();

  // ---- softmax epilogue: 16 rows x 16 b, threads 0..255
  if (tid < 256) {
    const int r = tid >> 4, b = tid & 15;
    const int row = row0 + r;
    if (row < TT) {
      float m = -3.4e38f;
      #pragma unroll
      for (int a = 0; a < 18; ++a) m = fmaxf(m, lg[r][b * 18 + a]);
      float sum = 0.f;
      #pragma unroll
      for (int a = 0; a < 18; ++a) sum += __expf(lg[r][b * 18 + a] - m);
      int act = actions[row];
      float aprob = __expf(lg[r][b * 18 + act] - m) / sum;

      float x0 = lg[r][288 + 2 * b], x1 = lg[r][288 + 2 * b + 1];
      float mm = fmaxf(x0, x1);
      float e0 = __expf(x0 - mm), e1 = __expf(x1 - mm);
      float inv = 1.f / (e0 + e1);

      float ms = -3.4e38f;
      #pragma unroll
      for (int j = 0; j < 16; ++j) ms = fmaxf(ms, lg[r][320 + j]);
      float ssum = 0.f;
      #pragma unroll
      for (int j = 0; j < 16; ++j) ssum += __expf(lg[r][320 + j] - ms);
      float stp = __expf(lg[r][320 + b] - ms) / ssum;

      coef[(size_t)row * NB + b] = make_float4(e0 * inv, e1 * inv, stp, aprob);
    } else if (row == TT) {
      // virtual step 2048: A = I, "action" prob = stop0 prob of row T
      float x0 = lg[r][288 + 2 * b], x1 = lg[r][288 + 2 * b + 1];
      float mm = fmaxf(x0, x1);
      float e0 = __expf(x0 - mm), e1 = __expf(x1 - mm);
      coef[(size_t)TT * NB + b] = make_float4(1.f, 0.f, 0.f, e0 / (e0 + e1));
    }
  }
}

// ---------------- kernel B: pass1 — chunk transfer matrices + w-vectors ----
__global__ __launch_bounds__(64) void pass1_kernel(
    const float4* __restrict__ coef,
    float* __restrict__ Wws, float* __restrict__ Mws)
{
  const int chunk = blockIdx.x * 4 + (threadIdx.x >> 4);
  const int c = threadIdx.x & 15;
  const int i0 = chunk * CLEN + 1;

  float G[16];
  #pragma unroll
  for (int r = 0; r < 16; ++r) G[r] = (r == c) ? 1.f : 0.f;

  float4 cfA[16], cfB[16];
  #pragma unroll
  for (int r = 0; r < 16; ++r) cfA[r] = coef[(size_t)i0 * 16 + r];
  #pragma unroll
  for (int r = 0; r < 16; ++r) cfB[r] = coef[(size_t)(i0 + 1) * 16 + r];

#define P1BODY(CUR, NXT, J)                                                  \
  {                                                                          \
    if ((J) + 2 < CLEN) {                                                    \
      _Pragma("unroll")                                                      \
      for (int r = 0; r < 16; ++r)                                           \
        NXT[r] = coef[(size_t)(i0 + (J) + 2) * 16 + r];                      \
    }                                                                        \
    float ta = 0.f, tb = 0.f, tc = 0.f, td = 0.f;                            \
    _Pragma("unroll")                                                        \
    for (int r = 0; r < 4; ++r) {                                            \
      ta = fmaf(CUR[r].y,      G[r],      ta);                               \
      tb = fmaf(CUR[r + 4].y,  G[r + 4],  tb);                               \
      tc = fmaf(CUR[r + 8].y,  G[r + 8],  tc);                               \
      td = fmaf(CUR[r + 12].y, G[r + 12], td);                               \
    }                                                                        \
    float et = EPEN * ((ta + tb) + (tc + td));                               \
    _Pragma("unroll")                                                        \
    for (int r = 0; r < 16; ++r)                                             \
      G[r] = fmaf(CUR[r].x, G[r], CUR[r].z * et);                            \
    float wa = 0.f, wb = 0.f, wc = 0.f, wd = 0.f;                            \
    _Pragma("unroll")                                                        \
    for (int r = 0; r < 4; ++r) {                                            \
      wa = fmaf(CUR[r].w,      G[r],      wa);                               \
      wb = fmaf(CUR[r + 4].w,  G[r + 4],  wb);                               \
      wc = fmaf(CUR[r + 8].w,  G[r + 8],  wc);                               \
      wd = fmaf(CUR[r + 12].w, G[r + 12], wd);                               \
    }                                                                        \
    Wws[(size_t)(chunk * CLEN + (J)) * 16 + c] = (wa + wb) + (wc + wd);      \
  }

  for (int j = 0; j < CLEN; j += 2) {
    P1BODY(cfA, cfB, j);
    P1BODY(cfB, cfA, j + 1);
  }
#undef P1BODY

  #pragma unroll
  for (int r = 0; r < 16; ++r)
    Mws[chunk * 256 + r * 16 + c] = G[r];
}

// ---------------- kernel C: pass2 — two-phase chunk walk ------------------
// Phase 1 (wave 0 only): serial 16x16 matvec chain, quad layout l = 4r+g:
// lane holds M[r][4g..4g+3] (Mws reads now fully coalesced) and p[4g..4g+3].
// Per chunk: FMA nest -> TWO quad_perm DPP adds (VALU pipe, replaces the
// ~120-cyc ds_swizzle stage) -> 4 parallel ds_bpermute gathers (was 8) ->
// readfirstlane exponent -> rescale. Summation tree (P0+P1)+(P2+P3) is
// bit-identical to the previous passing version; Ktot bookkeeping unchanged.
// Phase 2 (all 512 threads): 2048 log(w_j . p_chunk) terms in parallel.
__global__ __launch_bounds__(512) void pass2_kernel(
    const float4* __restrict__ coef,
    const float* __restrict__ Wws, const float* __restrict__ Mws,
    float* __restrict__ out)
{
  __shared__ float pbuf[NCHUNK][16];   // chunk-start scaled p vectors
  __shared__ float wacc[8];            // per-wave partial log sums

  const int tid = threadIdx.x;
  long long Ktot = 0;                  // only thread 0's value is used

  // ---------------- phase 1: serial chain, wave 0 only ----------------
  if (tid < 64) {
    const int r = tid >> 2, g = tid & 3;     // quad layout: lane = 4r+g
    float pj0 = coef[4 * g + 0].z;
    float pj1 = coef[4 * g + 1].z;
    float pj2 = coef[4 * g + 2].z;
    float pj3 = coef[4 * g + 3].z;

    const int moff = r * 16 + 4 * g;
    // bpermute byte addrs: y_{4g+j} lives in quad (4g+j) -> lane 16g+4j
    const int gb0 = 64 * g, gb1 = gb0 + 16, gb2 = gb0 + 32, gb3 = gb0 + 48;
    int Ecum = 0;

    // prefetch depth 8 (named regs; no runtime indexing -> no scratch)
    float4 mR0 = *(const float4*)&Mws[0 * 256 + moff];
    float4 mR1 = *(const float4*)&Mws[1 * 256 + moff];
    float4 mR2 = *(const float4*)&Mws[2 * 256 + moff];
    float4 mR3 = *(const float4*)&Mws[3 * 256 + moff];
    float4 mR4 = *(const float4*)&Mws[4 * 256 + moff];
    float4 mR5 = *(const float4*)&Mws[5 * 256 + moff];
    float4 mR6 = *(const float4*)&Mws[6 * 256 + moff];
    float4 mR7 = *(const float4*)&Mws[7 * 256 + moff];

#define P2BODY(K, MREG, KPF)                                                 \
    {                                                                        \
      if (r == 0)                                                            \
        *(float4*)&pbuf[(K)][4 * g] = make_float4(pj0, pj1, pj2, pj3);       \
      Ktot += 32LL * (long long)Ecum;                                        \
      float part = fmaf(MREG.x, pj0,                                         \
                   fmaf(MREG.y, pj1, fmaf(MREG.z, pj2, MREG.w * pj3)));      \
      if ((KPF) < NCHUNK)                                                    \
        MREG = *(const float4*)&Mws[(KPF) * 256 + moff];                     \
      /* quad rotate-add: lane g accumulates (Pg+Pg+1)+(Pg+2+Pg+3) */        \
      part += __int_as_float(__builtin_amdgcn_mov_dpp(                       \
          __float_as_int(part), 0x39, 0xF, 0xF, true));  /* quad ror 1 */    \
      part += __int_as_float(__builtin_amdgcn_mov_dpp(                       \
          __float_as_int(part), 0x4E, 0xF, 0xF, true));  /* quad ror 2 */    \
      int ip = __float_as_int(part);                                         \
      float n0 = __int_as_float(__builtin_amdgcn_ds_bpermute(gb0, ip));      \
      float n1 = __int_as_float(__builtin_amdgcn_ds_bpermute(gb1, ip));      \
      float n2 = __int_as_float(__builtin_amdgcn_ds_bpermute(gb2, ip));      \
      float n3 = __int_as_float(__builtin_amdgcn_ds_bpermute(gb3, ip));      \
      int y0b = __builtin_amdgcn_readfirstlane(__float_as_int(n0));          \
      int eb = (y0b >> 23) & 255;                                            \
      Ecum += eb - 127;                                                      \
      float sc = __int_as_float((254 - eb) << 23);                           \
      pj0 = n0 * sc; pj1 = n1 * sc; pj2 = n2 * sc; pj3 = n3 * sc;            \
    }

    for (int kb = 0; kb < NCHUNK; kb += 8) {
      P2BODY(kb + 0, mR0, kb + 8);
      P2BODY(kb + 1, mR1, kb + 9);
      P2BODY(kb + 2, mR2, kb + 10);
      P2BODY(kb + 3, mR3, kb + 11);
      P2BODY(kb + 4, mR4, kb + 12);
      P2BODY(kb + 5, mR5, kb + 13);
      P2BODY(kb + 6, mR6, kb + 14);
      P2BODY(kb + 7, mR7, kb + 15);
    }
#undef P2BODY
  }
  __syncthreads();

  // ---------------- phase 2: 2048 parallel log terms ----------------
  const int j0 = tid * 4;              // 4 consecutive steps, same chunk
  const int chunk = j0 >> 5;
  float p[16];
  #pragma unroll
  for (int c = 0; c < 16; ++c) p[c] = pbuf[chunk][c];

  float lacc = 0.f;
  #pragma unroll
  for (int jj = 0; jj < 4; ++jj) {
    const float* w = Wws + (size_t)(j0 + jj) * 16;
    float4 w0 = *(const float4*)(w);
    float4 w1 = *(const float4*)(w + 4);
    float4 w2 = *(const float4*)(w + 8);
    float4 w3 = *(const float4*)(w + 12);
    float s0 = fmaf(w0.x, p[0],  fmaf(w0.y, p[1],  fmaf(w0.z, p[2],  w0.w * p[3])));
    float s1 = fmaf(w1.x, p[4],  fmaf(w1.y, p[5],  fmaf(w1.z, p[6],  w1.w * p[7])));
    float s2 = fmaf(w2.x, p[8],  fmaf(w2.y, p[9],  fmaf(w2.z, p[10], w2.w * p[11])));
    float s3 = fmaf(w3.x, p[12], fmaf(w3.y, p[13], fmaf(w3.z, p[14], w3.w * p[15])));
    lacc += __logf((s0 + s1) + (s2 + s3));
  }

  if (tid == 0) {          // U0 term: sum_c coef[c].w * coef[c].z
    float U0 = 0.f;
    #pragma unroll
    for (int c = 0; c < 16; ++c) U0 = fmaf(coef[c].w, coef[c].z, U0);
    lacc += __logf(U0);
  }

  // wave reduce, then 8-entry double sum
  lacc += __shfl_xor(lacc, 1, 64);
  lacc += __shfl_xor(lacc, 2, 64);
  lacc += __shfl_xor(lacc, 4, 64);
  lacc += __shfl_xor(lacc, 8, 64);
  lacc += __shfl_xor(lacc, 16, 64);
  lacc += __shfl_xor(lacc, 32, 64);
  if ((tid & 63) == 0) wacc[tid >> 6] = lacc;
  __syncthreads();
  if (tid == 0) {
    double s = 0.0;
    #pragma unroll
    for (int i = 0; i < 8; ++i) s += (double)wacc[i];
    out[0] = (float)(s + 0.6931471805599453 * (double)Ktot);
  }
}

extern "C" void kernel_launch(void* const* d_in, const int* in_sizes, int n_in,
                              void* d_out, int out_size, void* d_ws, size_t ws_size,
                              hipStream_t stream) {
  const float* s_i = (const float*)d_in[0];
  const float* Wa  = (const float*)d_in[1];
  const float* Ws  = (const float*)d_in[2];
  const float* Wst = (const float*)d_in[3];
  const int*   act = (const int*)d_in[4];

  char* ws = (char*)d_ws;
  float4* coef = (float4*)ws;                        //   524,544 B
  float*  Wws  = (float*)(ws + 524544);              // + 131,072 B
  float*  Mws  = (float*)(ws + 524544 + 131072);     // +  65,536 B
  ushort* Wt2  = (ushort*)(ws + 721152);             // + 344,064 B
  ushort* Af   = (ushort*)(ws + 1065216);            // + 2,113,536 B (~3.2 MB)

  prep_kernel <<<600, 256, 0, stream>>>(Wa, Ws, Wst, s_i, Wt2, Af);
  proj_kernel <<<129, 512, 0, stream>>>(Af, Wt2, act, coef);
  pass1_kernel<<<16,  64,  0, stream>>>(coef, Wws, Mws);
  pass2_kernel<<<1,   512, 0, stream>>>(coef, Wws, Mws, (float*)d_out);
}